// Round 6
// baseline (701.009 us; speedup 1.0000x reference)
//
#include <hip/hip_runtime.h>
#include <math.h>

// ---------------------------------------------------------------------------
// MultiStreamCNN. R19: (a) fuse_mfma rewritten as LDS-staged 12-phase (c,ky)
// kernel: block = 1 row x 128px, per phase stage A-row (hi+lo 16KB) + 3 B
// taps (48KB) via global_load_lds (LDS = 65536B exactly), waves = 2px x 2oc
// quadrants, acc[4][4]. Cuts fuse L2 traffic 2.36GB -> ~0.8GB (A /9, B /4)
// and replaces 600cy L2/L3 fragment loads with LDS reads. FP order per
// output element identical (tc ascending, bh/bl/bh term order) -> MFMA
// results bitwise-same. (b) conv1 pool pad 32->33, conv2 pool pad 64->65
// (kills measured 16/32-way epilogue bank conflicts; address-only change).
// conv1/conv2 otherwise byte-identical to R18.
// ---------------------------------------------------------------------------

typedef __bf16 bf16x8 __attribute__((ext_vector_type(8)));
typedef float f32x4 __attribute__((ext_vector_type(4)));

static __device__ __forceinline__ ushort f2bf(float f) {
    unsigned u = __float_as_uint(f);
    unsigned r = (u + 0x7fffu + ((u >> 16) & 1u)) >> 16;   // RNE
    return (ushort)r;
}
static __device__ __forceinline__ float bf2f(ushort h) {
    return __uint_as_float(((unsigned)h) << 16);
}
static __device__ __forceinline__ void gl_lds16(const void* g, void* l) {
    __builtin_amdgcn_global_load_lds(
        (const __attribute__((address_space(1))) void*)g,
        (__attribute__((address_space(3))) void*)l, 16, 0, 0);
}

// ---------- w1prep: conv1 weights (both streams) -> packed hi|lo ------------
// W1p[s][oc][k] : k = c*9 + ky*3 + kx for k<27, zero-padded to 32.
__global__ __launch_bounds__(256) void w1prep(
    const float* __restrict__ w_rgb, const float* __restrict__ w_ir,
    uint* __restrict__ W1p)
{
    int i = blockIdx.x * 256 + threadIdx.x;
    if (i >= 2048) return;
    int s = i >> 10, r = i & 1023;
    int oc = r >> 5, k = r & 31;
    const float* w = s ? w_ir : w_rgb;
    float v = (k < 27) ? w[oc * 27 + k] : 0.f;   // [oc][c][ky][kx] linear == oc*27+k
    ushort h = f2bf(v);
    W1p[i] = (uint)h | ((uint)f2bf(v - bf2f(h)) << 16);
}

// ---------- Kernel A: conv3x3 (3->32) via MFMA + bias + relu + maxpool2 -----
__global__ __launch_bounds__(256) void conv1_mfma(
    const float* __restrict__ x, const uint* __restrict__ W1p,
    const float* __restrict__ bias, ushort* __restrict__ C1h,
    ushort* __restrict__ C1l)
{
    __shared__ uint S[3 * 4 * 132];          // packed hi|lo x tile, 6336 B
    __shared__ float pool[4][32][33];        // padded stride 33: no 16-way read conflicts

    const int seg = blockIdx.x, Y = blockIdx.y, b = blockIdx.z;
    const int tid = threadIdx.x, wsub = tid >> 6, lane = tid & 63;
    const int n = lane & 15, q = lane >> 4;

    // B fragments from global packed W1p (4KB, L2-hot): oc = nt*16+n, k = q*8+e
    uint4 bu0a = *(const uint4*)&W1p[n * 32 + q * 8];
    uint4 bu0b = *(const uint4*)&W1p[n * 32 + q * 8 + 4];
    uint4 bu1a = *(const uint4*)&W1p[(16 + n) * 32 + q * 8];
    uint4 bu1b = *(const uint4*)&W1p[(16 + n) * 32 + q * 8 + 4];

    // stage x rows 2Y-1..2Y+2, cols seg*128-1..+128 (130 used, stride 132)
    const int ih0 = 2 * Y - 1, iw0 = seg * 128 - 1;
    for (int i = tid; i < 1584; i += 256) {
        int c = i / 528, rem = i - c * 528;
        int r = rem / 132, cc = rem - r * 132;
        int ih = ih0 + r, iw = iw0 + cc;
        float v = 0.f;
        if (cc < 130 && ih >= 0 && ih < 512 && iw >= 0 && iw < 512)
            v = x[((b * 3 + c) * 512 + ih) * 512 + iw];
        ushort h = f2bf(v);
        S[i] = (uint)h | ((uint)f2bf(v - bf2f(h)) << 16);
    }

    // unpack B into bf16x8 fragments (hi from low16, lo from high16)
    uint4 bh0v, bl0v, bh1v, bl1v;
    {
        uint u0[8], u1[8];
        *(uint4*)&u0[0] = bu0a; *(uint4*)&u0[4] = bu0b;
        *(uint4*)&u1[0] = bu1a; *(uint4*)&u1[4] = bu1b;
        uint* bh0 = (uint*)&bh0v; uint* bl0 = (uint*)&bl0v;
        uint* bh1 = (uint*)&bh1v; uint* bl1 = (uint*)&bl1v;
#pragma unroll
        for (int j = 0; j < 4; ++j) {
            bh0[j] = (u0[2 * j] & 0xffffu) | (u0[2 * j + 1] << 16);
            bl0[j] = (u0[2 * j] >> 16) | (u0[2 * j + 1] & 0xffff0000u);
            bh1[j] = (u1[2 * j] & 0xffffu) | (u1[2 * j + 1] << 16);
            bl1[j] = (u1[2 * j] >> 16) | (u1[2 * j + 1] & 0xffff0000u);
        }
    }
    bf16x8 Bh0 = __builtin_bit_cast(bf16x8, bh0v);
    bf16x8 Bl0 = __builtin_bit_cast(bf16x8, bl0v);
    bf16x8 Bh1 = __builtin_bit_cast(bf16x8, bh1v);
    bf16x8 Bl1 = __builtin_bit_cast(bf16x8, bl1v);

    // per-lane gather offsets: k = q*8+e -> (c,ky,kx)
    int idx[8];
    const int off0 = (wsub & 1) * 132 + (wsub >> 1) * 64 + n;
#pragma unroll
    for (int e = 0; e < 8; ++e) {
        int k = q * 8 + e;
        int c = (k >= 18) ? ((k >= 27) ? 3 : 2) : ((k >= 9) ? 1 : 0);
        int t = k - c * 9;
        int ky = (t >= 6) ? 2 : ((t >= 3) ? 1 : 0);
        int kx = t - ky * 3;
        idx[e] = (k < 27) ? ((c * 4 + ky) * 132 + kx + off0) : 0;  // k>=27: B=0
    }
    __syncthreads();

    f32x4 acc[4][2];
#pragma unroll
    for (int mt = 0; mt < 4; ++mt)
#pragma unroll
        for (int nt = 0; nt < 2; ++nt) acc[mt][nt] = (f32x4){0.f, 0.f, 0.f, 0.f};

#pragma unroll
    for (int mt = 0; mt < 4; ++mt) {
        uint u[8];
#pragma unroll
        for (int e = 0; e < 8; ++e) u[e] = S[idx[e] + mt * 16];
        uint4 ahv, alv;
        uint* ah = (uint*)&ahv;
        uint* al = (uint*)&alv;
#pragma unroll
        for (int j = 0; j < 4; ++j) {
            ah[j] = (u[2 * j] & 0xffffu) | (u[2 * j + 1] << 16);
            al[j] = (u[2 * j] >> 16) | (u[2 * j + 1] & 0xffff0000u);
        }
        bf16x8 Ah = __builtin_bit_cast(bf16x8, ahv);
        bf16x8 Al = __builtin_bit_cast(bf16x8, alv);
        __builtin_amdgcn_s_setprio(1);
        acc[mt][0] = __builtin_amdgcn_mfma_f32_16x16x32_bf16(Ah, Bh0, acc[mt][0], 0, 0, 0);
        acc[mt][1] = __builtin_amdgcn_mfma_f32_16x16x32_bf16(Ah, Bh1, acc[mt][1], 0, 0, 0);
        acc[mt][0] = __builtin_amdgcn_mfma_f32_16x16x32_bf16(Ah, Bl0, acc[mt][0], 0, 0, 0);
        acc[mt][1] = __builtin_amdgcn_mfma_f32_16x16x32_bf16(Ah, Bl1, acc[mt][1], 0, 0, 0);
        acc[mt][0] = __builtin_amdgcn_mfma_f32_16x16x32_bf16(Al, Bh0, acc[mt][0], 0, 0, 0);
        acc[mt][1] = __builtin_amdgcn_mfma_f32_16x16x32_bf16(Al, Bh1, acc[mt][1], 0, 0, 0);
        __builtin_amdgcn_s_setprio(0);
    }

    // pool x-pairs in-lane (D rows q*4+r are conv x), then row-pairs via LDS
#pragma unroll
    for (int mt = 0; mt < 4; ++mt)
#pragma unroll
        for (int nt = 0; nt < 2; ++nt) {
            int oc = nt * 16 + n;
            int plx = mt * 8 + q * 2;
            pool[wsub][plx][oc]     = fmaxf(acc[mt][nt][0], acc[mt][nt][1]);
            pool[wsub][plx + 1][oc] = fmaxf(acc[mt][nt][2], acc[mt][nt][3]);
        }
    __syncthreads();
    {
        int plx = tid >> 2, ocq = tid & 3;       // plx in [0,64), oc = ocq*8..+8
        int wp = plx >> 5, pl = plx & 31;
        __attribute__((aligned(16))) ushort hb[8], lb[8];
#pragma unroll
        for (int e = 0; e < 8; ++e) {
            int oc = ocq * 8 + e;
            float v = fmaxf(pool[wp * 2][pl][oc], pool[wp * 2 + 1][pl][oc]);
            v = fmaxf(v + bias[oc], 0.f);
            ushort h = f2bf(v);
            hb[e] = h;
            lb[e] = f2bf(v - bf2f(h));
        }
        int ow = seg * 64 + plx;
        size_t base = (((size_t)((b * 256 + Y) * 256 + ow)) << 5) + ocq * 8;
        *(uint4*)(C1h + base) = *(const uint4*)hb;
        *(uint4*)(C1l + base) = *(const uint4*)lb;
    }
}

// ---------- Kernel B: conv2, ky-phase LDS-staged A + B ----------------------
__global__ __launch_bounds__(256) void conv2_mfma(
    const ushort* __restrict__ C1h, const ushort* __restrict__ C1l,
    const float* __restrict__ w2, const float* __restrict__ bias,
    ushort* __restrict__ Ahi, ushort* __restrict__ Alo, int stream_base)
{
    // A: [hl][rs][132 slots][32ch] ushort = 33792 B; B: 2x 3*2048 ushorts.
    __shared__ __attribute__((aligned(16))) char lds[58368];
    ushort* BhL = (ushort*)(lds + 33792);
    ushort* BlL = (ushort*)(lds + 46080);
    float (*pool)[32][65] = (float (*)[32][65])lds;  // padded stride 65 (union after phases)

    const int seg = blockIdx.x, Y = blockIdx.y, b = blockIdx.z;
    const int tid = threadIdx.x, wsub = tid >> 6, lane = tid & 63;
    const int n = lane & 15, q = lane >> 4;
    const int rs = wsub & 1;               // wave conv-row select
    const int xs = wsub >> 1;              // wave x-half within block

    const uint4 zero4 = make_uint4(0u, 0u, 0u, 0u);

    f32x4 acc[4][4];
#pragma unroll
    for (int mt = 0; mt < 4; ++mt)
#pragma unroll
        for (int nt = 0; nt < 4; ++nt) acc[mt][nt] = (f32x4){0.f, 0.f, 0.f, 0.f};

    for (int ky = 0; ky < 3; ++ky) {
        if (ky) __syncthreads();           // prior phase's LDS reads done

        // ---- stage A: wave (hl = wsub>>1, rsS = wsub&1) stages one row -----
        {
            const int hl = wsub >> 1, rsS = wsub & 1;
            const int yy = 2 * Y + rsS + ky - 1;
            char* dstbase = lds + hl * 16896 + rsS * 8448 + 64;  // slots 1..128
            if (yy >= 0 && yy < 256) {
                const ushort* src = (hl ? C1l : C1h)
                    + ((size_t)(b * 256 + yy) * 256 + seg * 128) * 32;
                const char* s8 = (const char*)src + lane * 16;
#pragma unroll
                for (int j = 0; j < 8; ++j)
                    gl_lds16(s8 + j * 1024, dstbase + j * 1024);
            } else {
#pragma unroll
                for (int j = 0; j < 8; ++j)
                    *(uint4*)(dstbase + j * 1024 + lane * 16) = zero4;
            }
        }
        // ---- edge slots 0 (xp=seg*128-1) and 129 (xp=seg*128+128) ----------
        if (tid < 32) {
            int combo = tid >> 3;          // hl*2 + rsE
            int hl = combo >> 1, rsE = combo & 1;
            int e = (tid >> 2) & 1, part = tid & 3;
            int yy = 2 * Y + rsE + ky - 1;
            int xp = seg * 128 + (e ? 128 : -1);
            uint4 v = zero4;
            if (yy >= 0 && yy < 256 && xp >= 0 && xp < 256) {
                const ushort* src = (hl ? C1l : C1h)
                    + ((size_t)(b * 256 + yy) * 256 + xp) * 32 + part * 8;
                v = *(const uint4*)src;
            }
            *(uint4*)(lds + hl * 16896 + rsE * 8448 + (e ? 129 * 64 : 0) + part * 16) = v;
        }
        // ---- stage B: taps ky*3 .. ky*3+2 ---------------------------------
        for (int i = tid; i < 6144; i += 256) {
            int t = ky * 3 + (i >> 11), r = i & 2047;
            float v = w2[r * 9 + t];
            ushort h = f2bf(v);
            BhL[i] = h;
            BlL[i] = f2bf(v - bf2f(h));
        }
        __syncthreads();                   // drains vmcnt -> A landed; B visible

        for (int kx = 0; kx < 3; ++kx) {
            uint4 cH[4], cL[4];
#pragma unroll
            for (int mt = 0; mt < 4; ++mt) {
                int off = rs * 8448 + (xs * 64 + mt * 16 + n + kx) * 64 + q * 16;
                cH[mt] = *(const uint4*)(lds + off);
                cL[mt] = *(const uint4*)(lds + 16896 + off);
            }
            bf16x8 bh[4], bl[4];
#pragma unroll
            for (int nt = 0; nt < 4; ++nt) {
                int off = kx * 2048 + (nt * 16 + n) * 32 + q * 8;
                bh[nt] = __builtin_bit_cast(bf16x8, *(const uint4*)&BhL[off]);
                bl[nt] = __builtin_bit_cast(bf16x8, *(const uint4*)&BlL[off]);
            }
            // step-outer MFMA order (dep distance 16), identical FP order
            __builtin_amdgcn_s_setprio(1);
#pragma unroll
            for (int mt = 0; mt < 4; ++mt) {
                bf16x8 ah = __builtin_bit_cast(bf16x8, cH[mt]);
#pragma unroll
                for (int nt = 0; nt < 4; ++nt)
                    acc[mt][nt] = __builtin_amdgcn_mfma_f32_16x16x32_bf16(ah, bh[nt], acc[mt][nt], 0, 0, 0);
            }
#pragma unroll
            for (int mt = 0; mt < 4; ++mt) {
                bf16x8 ah = __builtin_bit_cast(bf16x8, cH[mt]);
#pragma unroll
                for (int nt = 0; nt < 4; ++nt)
                    acc[mt][nt] = __builtin_amdgcn_mfma_f32_16x16x32_bf16(ah, bl[nt], acc[mt][nt], 0, 0, 0);
            }
#pragma unroll
            for (int mt = 0; mt < 4; ++mt) {
                bf16x8 al = __builtin_bit_cast(bf16x8, cL[mt]);
#pragma unroll
                for (int nt = 0; nt < 4; ++nt)
                    acc[mt][nt] = __builtin_amdgcn_mfma_f32_16x16x32_bf16(al, bh[nt], acc[mt][nt], 0, 0, 0);
            }
            __builtin_amdgcn_s_setprio(0);
        }
    }

    __syncthreads();   // all LDS reads done; safe to overwrite with pool

#pragma unroll
    for (int mt = 0; mt < 4; ++mt)
#pragma unroll
        for (int nt = 0; nt < 4; ++nt) {
            int oc = nt * 16 + n;
            int plx = mt * 8 + q * 2;
            pool[wsub][plx][oc]     = fmaxf(acc[mt][nt][0], acc[mt][nt][1]);
            pool[wsub][plx + 1][oc] = fmaxf(acc[mt][nt][2], acc[mt][nt][3]);
        }
    __syncthreads();

    {
        int plx = tid >> 2, ocq = tid & 3;
        int wp = plx >> 5, pl = plx & 31;
        __attribute__((aligned(16))) ushort hb[16], lb[16];
#pragma unroll
        for (int e = 0; e < 16; ++e) {
            int oc = ocq * 16 + e;
            float v = fmaxf(pool[wp * 2][pl][oc], pool[wp * 2 + 1][pl][oc]);
            v = fmaxf(v + bias[oc], 0.f);
            ushort h = f2bf(v);
            hb[e] = h;
            lb[e] = f2bf(v - bf2f(h));
        }
        int gx = seg * 64 + plx;
        int cpl = (stream_base >> 5) + (ocq >> 1);
        int cho = (ocq & 1) * 16;
        size_t base = (((size_t)(((b * 4 + cpl) * 128 + Y) * 128 + gx)) << 5) + cho;
        uint4* dh = (uint4*)(Ahi + base);
        uint4* dl = (uint4*)(Alo + base);
        dh[0] = *(const uint4*)&hb[0];
        dh[1] = *(const uint4*)&hb[8];
        dl[0] = *(const uint4*)&lb[0];
        dl[1] = *(const uint4*)&lb[8];
    }
}

// ---------- wprep: fuse_w fp32 -> fragment-ordered bf16 hi/lo ---------------
// CHUNK-MAJOR: Wf[c][t][oc][kk] = W[oc][ic=c*32+kk][ky=t/3][kx=t%3]
__global__ __launch_bounds__(256) void wprep(
    const float* __restrict__ fw, ushort* __restrict__ Whi,
    ushort* __restrict__ Wlo)
{
    int idx = blockIdx.x * 256 + threadIdx.x;
    if (idx >= 147456) return;
    int kk = idx & 31;
    int oc = (idx >> 5) & 127;
    int ct = idx >> 12;           // 0..35 = c*9 + t
    int c = ct / 9, t = ct - c * 9;
    int ic = c * 32 + kk;
    int ky = t / 3, kx = t - ky * 3;
    float v = fw[((oc * 128 + ic) * 3 + ky) * 3 + kx];
    ushort h = f2bf(v);
    Whi[idx] = h;
    Wlo[idx] = f2bf(v - bf2f(h));
}

// ---------- Kernel C: fuse conv, LDS-staged 12-phase (c,ky) -----------------
// Block = 1 conv row x 128px (grid 8 x 128). Waves: p = wsub&1 (px half),
// o = wsub>>1 (oc half). Per phase (c,ky): stage A row y+ky-1 (hi+lo 16KB)
// + B taps ky*3..+2 (48KB) via global_load_lds; compute kx=0..2 from LDS.
// LDS = 65536 B exactly. acc[4][4] = 64 regs. FP order per output element
// identical to R13-R18 fuse (tc = c*9+ky*3+kx ascending; bh,bl,bh terms).
__global__ __launch_bounds__(256, 2) void fuse_mfma(
    const ushort* __restrict__ Ahi, const ushort* __restrict__ Alo,
    const ushort* __restrict__ Whi, const ushort* __restrict__ Wlo,
    const float* __restrict__ bias, float* __restrict__ featsum)
{
    // layout: A-hi [128 slots][32] @0 (8192B); A-lo @8192;
    //         B-hi [3][128][32] @16384 (24576B); B-lo @40960.
    __shared__ __attribute__((aligned(16))) char lds[65536];

    const int b = blockIdx.x, y = blockIdx.y;
    const int tid = threadIdx.x, wsub = tid >> 6, lane = tid & 63;
    const int n = lane & 15, q = lane >> 4;
    const int p = wsub & 1, o = wsub >> 1;

    const uint4 zero4 = make_uint4(0u, 0u, 0u, 0u);
    const bool badL = (p == 0) & (n == 0);    // kx=0, mt=0: xp = -1
    const bool badR = (p == 1) & (n == 15);   // kx=2, mt=3: xp = 128

    f32x4 acc[4][4];
#pragma unroll
    for (int mt = 0; mt < 4; ++mt)
#pragma unroll
        for (int g = 0; g < 4; ++g) acc[mt][g] = (f32x4){0.f, 0.f, 0.f, 0.f};

    for (int c = 0; c < 4; ++c) {
        for (int ky = 0; ky < 3; ++ky) {
            if (c | ky) __syncthreads();   // prior phase's LDS reads done

            // ---- stage: wave0 = A (16 x 1KB), waves1-3 = B (16 x 1KB each) --
            if (wsub == 0) {
                const int yy = y + ky - 1;
                if (yy >= 0 && yy < 128) {
                    const char* sH = (const char*)(Ahi + ((size_t)((b * 4 + c) * 128 + yy)) * 4096) + lane * 16;
                    const char* sL = (const char*)(Alo + ((size_t)((b * 4 + c) * 128 + yy)) * 4096) + lane * 16;
#pragma unroll
                    for (int j = 0; j < 8; ++j) {
                        gl_lds16(sH + j * 1024, lds + j * 1024);
                        gl_lds16(sL + j * 1024, lds + 8192 + j * 1024);
                    }
                } else {
#pragma unroll
                    for (int j = 0; j < 16; ++j)
                        *(uint4*)(lds + j * 1024 + lane * 16) = zero4;
                }
            } else {
                const size_t woff = (size_t)(c * 9 + ky * 3) * 4096;   // ushorts
                const int bc0 = (wsub - 1) * 16;                       // 0/16/32
#pragma unroll
                for (int j = 0; j < 16; ++j) {
                    int bc = bc0 + j;                                  // 0..47
                    const ushort* base = (bc < 24) ? (Whi + woff) : (Wlo + woff);
                    int co = (bc < 24) ? bc : (bc - 24);
                    gl_lds16((const char*)base + co * 1024 + lane * 16,
                             lds + 16384 + bc * 1024);
                }
            }
            __syncthreads();               // drains vmcnt: A+B landed

#pragma unroll
            for (int kx = 0; kx < 3; ++kx) {
                // B fragments (per-wave oc slice)
                bf16x8 bh[4], bl[4];
#pragma unroll
                for (int g = 0; g < 4; ++g) {
                    int boff = 16384 + kx * 8192 + (o * 64 + g * 16 + n) * 64 + q * 16;
                    bh[g] = __builtin_bit_cast(bf16x8, *(const uint4*)(lds + boff));
                    bl[g] = __builtin_bit_cast(bf16x8, *(const uint4*)(lds + boff + 24576));
                }
                // A fragments
                uint4 cH[4], cL[4];
#pragma unroll
                for (int mt = 0; mt < 4; ++mt) {
                    int s = p * 64 + mt * 16 + n + kx - 1;
                    if (kx == 0 && mt == 0) s = (s < 0) ? 0 : s;
                    if (kx == 2 && mt == 3) s = (s > 127) ? 127 : s;
                    int aoff = s * 64 + q * 16;
                    cH[mt] = *(const uint4*)(lds + aoff);
                    cL[mt] = *(const uint4*)(lds + 8192 + aoff);
                }
                if (kx == 0) { cH[0] = badL ? zero4 : cH[0]; cL[0] = badL ? zero4 : cL[0]; }
                if (kx == 2) { cH[3] = badR ? zero4 : cH[3]; cL[3] = badR ? zero4 : cL[3]; }

                // per-acc term order: bh, bl, bh (identical to prior fuse)
#pragma unroll
                for (int g = 0; g < 4; ++g) {
#pragma unroll
                    for (int mt = 0; mt < 4; ++mt) {
                        bf16x8 ah = __builtin_bit_cast(bf16x8, cH[mt]);
                        acc[mt][g] = __builtin_amdgcn_mfma_f32_16x16x32_bf16(ah, bh[g], acc[mt][g], 0, 0, 0);
                    }
#pragma unroll
                    for (int mt = 0; mt < 4; ++mt) {
                        bf16x8 ah = __builtin_bit_cast(bf16x8, cH[mt]);
                        acc[mt][g] = __builtin_amdgcn_mfma_f32_16x16x32_bf16(ah, bl[g], acc[mt][g], 0, 0, 0);
                    }
#pragma unroll
                    for (int mt = 0; mt < 4; ++mt) {
                        bf16x8 al = __builtin_bit_cast(bf16x8, cL[mt]);
                        acc[mt][g] = __builtin_amdgcn_mfma_f32_16x16x32_bf16(al, bh[g], acc[mt][g], 0, 0, 0);
                    }
                }
            }
        }
    }

    __syncthreads();   // all LDS reads done; reuse lds for partials
    float* partial = (float*)lds;          // [2][128]

    // lane (q,n) of tile (mt,g): D[px = p*64 + mt*16 + q*4 + r][oc = o*64 + g*16 + n]
#pragma unroll
    for (int g = 0; g < 4; ++g) {
        float bv = bias[o * 64 + g * 16 + n];
        float v = 0.f;
#pragma unroll
        for (int mt = 0; mt < 4; ++mt)
#pragma unroll
            for (int r = 0; r < 4; ++r) v += fmaxf(acc[mt][g][r] + bv, 0.f);
        v += __shfl_xor(v, 16);
        v += __shfl_xor(v, 32);
        if (lane < 16) partial[p * 128 + o * 64 + g * 16 + lane] = v;
    }
    __syncthreads();
    if (tid < 128)
        atomicAdd(&featsum[b * 128 + tid], partial[tid] + partial[128 + tid]);
}

// ---------- Kernel D: det head + sigmoid + NMS + outputs --------------------
__global__ void det_nms(const float* __restrict__ featsum,
                        const float* __restrict__ dw, const float* __restrict__ db,
                        float* __restrict__ out)
{
    const int b = threadIdx.x;
    if (b >= 8) return;
    const float inv = 1.0f / 16384.0f;

    float p[18];
    for (int j = 0; j < 18; ++j) {
        float a = db[j];
        const float* wp = &dw[j * 128];
        const float* f = &featsum[b * 128];
        for (int c = 0; c < 128; ++c) a = fmaf(wp[c], f[c] * inv, a);
        p[j] = a;
    }
    for (int a = 0; a < 3; ++a)
        for (int e = 0; e < 6; ++e) out[b * 18 + a * 6 + e] = p[a * 6 + e];

    float bx[3][4], sc[3];
    bool ck[3];
    for (int a = 0; a < 3; ++a) {
        for (int k = 0; k < 4; ++k) {
            bx[a][k] = p[a * 6 + k];
            out[144 + b * 12 + a * 4 + k] = bx[a][k];
        }
        float sg = 1.f / (1.f + expf(-p[a * 6 + 4]));
        sc[a] = sg;
        ck[a] = sg > 0.5f;
        out[240 + b * 3 + a] = sg;
    }

    float key[3];
    int order[3];
    bool used[3] = {false, false, false};
    for (int a = 0; a < 3; ++a) key[a] = ck[a] ? sc[a] : -INFINITY;
    for (int i = 0; i < 3; ++i) {
        int best = -1;
        float bk = 0.f;
        for (int a = 0; a < 3; ++a) {
            if (used[a]) continue;
            if (best < 0 || key[a] > bk) { best = a; bk = key[a]; }
        }
        order[i] = best;
        used[best] = true;
    }

    float X1[3], Y1[3], X2[3], Y2[3], AR[3];
    for (int i = 0; i < 3; ++i) {
        int o = order[i];
        X1[i] = bx[o][0]; Y1[i] = bx[o][1];
        X2[i] = bx[o][2]; Y2[i] = bx[o][3];
        AR[i] = (X2[i] - X1[i]) * (Y2[i] - Y1[i]);
    }
    bool suppressed[3] = {false, false, false}, keep_s[3];
    for (int i = 0; i < 3; ++i) {
        bool valid = !suppressed[i];
        keep_s[i] = valid;
        if (valid) {
            for (int j = i + 1; j < 3; ++j) {
                float ix1 = fmaxf(X1[i], X1[j]), iy1 = fmaxf(Y1[i], Y1[j]);
                float ix2 = fminf(X2[i], X2[j]), iy2 = fminf(Y2[i], Y2[j]);
                float inter = fmaxf(ix2 - ix1, 0.f) * fmaxf(iy2 - iy1, 0.f);
                float iou = inter / (AR[i] + AR[j] - inter);
                if (iou > 0.5f) suppressed[j] = true;
            }
        }
    }
    bool keep[3];
    for (int i = 0; i < 3; ++i) keep[order[i]] = keep_s[i];
    for (int a = 0; a < 3; ++a)
        out[264 + b * 3 + a] = (keep[a] && ck[a]) ? 1.f : 0.f;
}

__global__ void zero_feat(float* __restrict__ p)
{
    int i = blockIdx.x * 256 + threadIdx.x;
    if (i < 1024) p[i] = 0.f;
}

// ---------------------------------------------------------------------------
extern "C" void kernel_launch(void* const* d_in, const int* in_sizes, int n_in,
                              void* d_out, int out_size, void* d_ws, size_t ws_size,
                              hipStream_t stream)
{
    const float* x      = (const float*)d_in[0];
    const float* rgb_w1 = (const float*)d_in[1];
    const float* rgb_b1 = (const float*)d_in[2];
    const float* rgb_w2 = (const float*)d_in[3];
    const float* rgb_b2 = (const float*)d_in[4];
    const float* ir_w1  = (const float*)d_in[5];
    const float* ir_b1  = (const float*)d_in[6];
    const float* ir_w2  = (const float*)d_in[7];
    const float* ir_b2  = (const float*)d_in[8];
    const float* fuse_w = (const float*)d_in[9];
    const float* fuse_b = (const float*)d_in[10];
    const float* det_w  = (const float*)d_in[11];
    const float* det_b  = (const float*)d_in[12];
    float* out = (float*)d_out;

    char* ws = (char*)d_ws;
    ushort* C1h  = (ushort*)(ws);                         // 33,554,432 B
    ushort* C1l  = (ushort*)(ws + 33554432);              // 33,554,432 B
    // post-conv2 reuse of the C1 region:
    ushort* Whi  = (ushort*)(ws);                         // 294,912 B
    ushort* Wlo  = (ushort*)(ws + 299008);                // 294,912 B
    float*  feat = (float*)(ws + 598016);                 // 4,096 B
    ushort* Ahi  = (ushort*)(ws + 67108864);              // 33,554,432 B
    ushort* Alo  = (ushort*)(ws + 100663296);             // 33,554,432 B
    // W1p (8 KB) parked in the TAIL of Alo: bytes [134209536, 134217728).
    // Written ONLY by conv2_mfma(ir) (plane b=7,cpl=3), after both
    // conv1_mfma dispatches have consumed W1p.
    uint*   W1p  = (uint*)(ws + 134209536);

    dim3 blk(256);
    hipLaunchKernelGGL(w1prep, dim3(8), blk, 0, stream, rgb_w1, ir_w1, W1p);
    hipLaunchKernelGGL(conv1_mfma, dim3(4, 256, 8), blk, 0, stream, x, W1p, rgb_b1, C1h, C1l);
    hipLaunchKernelGGL(conv2_mfma, dim3(2, 128, 8), blk, 0, stream, C1h, C1l, rgb_w2, rgb_b2, Ahi, Alo, 0);
    hipLaunchKernelGGL(conv1_mfma, dim3(4, 256, 8), blk, 0, stream, x, W1p + 1024, ir_b1, C1h, C1l);
    hipLaunchKernelGGL(conv2_mfma, dim3(2, 128, 8), blk, 0, stream, C1h, C1l, ir_w2, ir_b2, Ahi, Alo, 64);
    hipLaunchKernelGGL(wprep, dim3(576), blk, 0, stream, fuse_w, Whi, Wlo);
    hipLaunchKernelGGL(zero_feat, dim3(4), blk, 0, stream, feat);
    hipLaunchKernelGGL(fuse_mfma, dim3(8, 128), blk, 0, stream, Ahi, Alo, Whi, Wlo, fuse_b, feat);
    hipLaunchKernelGGL(det_nms, dim3(1), dim3(64), 0, stream, feat, det_w, det_b, out);
}

// Round 7
// 519.682 us; speedup vs baseline: 1.3489x; 1.3489x over previous
//
#include <hip/hip_runtime.h>
#include <math.h>

// ---------------------------------------------------------------------------
// MultiStreamCNN. R20: (a) fuse_mfma reverted byte-exact to R17 (122 us
// plateau; R19's LDS rewrite spilled 312MB scratch + 9.4M bank conflicts).
// (b) conv2: XOR bank-swizzle on BOTH LDS tensors. A is gl_lds-staged ->
// swizzle via pre-swizzled per-lane GLOBAL source (lane*16 ^ f<<4,
// f=(((lane>>2)+1)>>1)&3) + matching XOR on read (q ^ ((sidx>>1)&3));
// edge slots 0/129 have f=0 (unchanged). B is ds_write-staged -> swizzled
// write index (kk ^= ((oc>>1)&3)<<3) + read chunk q ^ ((n>>1)&3). Fixes the
// 64B-lane-stride 8-req/bank pattern (R19 measured 9.4M conflicts on the
// identical layout) down to the free 2/bank. Pool pads + conv setprio kept.
// ---------------------------------------------------------------------------

typedef __bf16 bf16x8 __attribute__((ext_vector_type(8)));
typedef float f32x4 __attribute__((ext_vector_type(4)));

static __device__ __forceinline__ ushort f2bf(float f) {
    unsigned u = __float_as_uint(f);
    unsigned r = (u + 0x7fffu + ((u >> 16) & 1u)) >> 16;   // RNE
    return (ushort)r;
}
static __device__ __forceinline__ float bf2f(ushort h) {
    return __uint_as_float(((unsigned)h) << 16);
}
static __device__ __forceinline__ void gl_lds16(const void* g, void* l) {
    __builtin_amdgcn_global_load_lds(
        (const __attribute__((address_space(1))) void*)g,
        (__attribute__((address_space(3))) void*)l, 16, 0, 0);
}

// ---------- w1prep: conv1 weights (both streams) -> packed hi|lo ------------
__global__ __launch_bounds__(256) void w1prep(
    const float* __restrict__ w_rgb, const float* __restrict__ w_ir,
    uint* __restrict__ W1p)
{
    int i = blockIdx.x * 256 + threadIdx.x;
    if (i >= 2048) return;
    int s = i >> 10, r = i & 1023;
    int oc = r >> 5, k = r & 31;
    const float* w = s ? w_ir : w_rgb;
    float v = (k < 27) ? w[oc * 27 + k] : 0.f;   // [oc][c][ky][kx] linear == oc*27+k
    ushort h = f2bf(v);
    W1p[i] = (uint)h | ((uint)f2bf(v - bf2f(h)) << 16);
}

// ---------- Kernel A: conv3x3 (3->32) via MFMA + bias + relu + maxpool2 -----
__global__ __launch_bounds__(256) void conv1_mfma(
    const float* __restrict__ x, const uint* __restrict__ W1p,
    const float* __restrict__ bias, ushort* __restrict__ C1h,
    ushort* __restrict__ C1l)
{
    __shared__ uint S[3 * 4 * 132];          // packed hi|lo x tile, 6336 B
    __shared__ float pool[4][32][33];        // padded stride 33: no epilogue conflicts

    const int seg = blockIdx.x, Y = blockIdx.y, b = blockIdx.z;
    const int tid = threadIdx.x, wsub = tid >> 6, lane = tid & 63;
    const int n = lane & 15, q = lane >> 4;

    // B fragments from global packed W1p (4KB, L2-hot): oc = nt*16+n, k = q*8+e
    uint4 bu0a = *(const uint4*)&W1p[n * 32 + q * 8];
    uint4 bu0b = *(const uint4*)&W1p[n * 32 + q * 8 + 4];
    uint4 bu1a = *(const uint4*)&W1p[(16 + n) * 32 + q * 8];
    uint4 bu1b = *(const uint4*)&W1p[(16 + n) * 32 + q * 8 + 4];

    // stage x rows 2Y-1..2Y+2, cols seg*128-1..+128 (130 used, stride 132)
    const int ih0 = 2 * Y - 1, iw0 = seg * 128 - 1;
    for (int i = tid; i < 1584; i += 256) {
        int c = i / 528, rem = i - c * 528;
        int r = rem / 132, cc = rem - r * 132;
        int ih = ih0 + r, iw = iw0 + cc;
        float v = 0.f;
        if (cc < 130 && ih >= 0 && ih < 512 && iw >= 0 && iw < 512)
            v = x[((b * 3 + c) * 512 + ih) * 512 + iw];
        ushort h = f2bf(v);
        S[i] = (uint)h | ((uint)f2bf(v - bf2f(h)) << 16);
    }

    // unpack B into bf16x8 fragments (hi from low16, lo from high16)
    uint4 bh0v, bl0v, bh1v, bl1v;
    {
        uint u0[8], u1[8];
        *(uint4*)&u0[0] = bu0a; *(uint4*)&u0[4] = bu0b;
        *(uint4*)&u1[0] = bu1a; *(uint4*)&u1[4] = bu1b;
        uint* bh0 = (uint*)&bh0v; uint* bl0 = (uint*)&bl0v;
        uint* bh1 = (uint*)&bh1v; uint* bl1 = (uint*)&bl1v;
#pragma unroll
        for (int j = 0; j < 4; ++j) {
            bh0[j] = (u0[2 * j] & 0xffffu) | (u0[2 * j + 1] << 16);
            bl0[j] = (u0[2 * j] >> 16) | (u0[2 * j + 1] & 0xffff0000u);
            bh1[j] = (u1[2 * j] & 0xffffu) | (u1[2 * j + 1] << 16);
            bl1[j] = (u1[2 * j] >> 16) | (u1[2 * j + 1] & 0xffff0000u);
        }
    }
    bf16x8 Bh0 = __builtin_bit_cast(bf16x8, bh0v);
    bf16x8 Bl0 = __builtin_bit_cast(bf16x8, bl0v);
    bf16x8 Bh1 = __builtin_bit_cast(bf16x8, bh1v);
    bf16x8 Bl1 = __builtin_bit_cast(bf16x8, bl1v);

    // per-lane gather offsets: k = q*8+e -> (c,ky,kx)
    int idx[8];
    const int off0 = (wsub & 1) * 132 + (wsub >> 1) * 64 + n;
#pragma unroll
    for (int e = 0; e < 8; ++e) {
        int k = q * 8 + e;
        int c = (k >= 18) ? ((k >= 27) ? 3 : 2) : ((k >= 9) ? 1 : 0);
        int t = k - c * 9;
        int ky = (t >= 6) ? 2 : ((t >= 3) ? 1 : 0);
        int kx = t - ky * 3;
        idx[e] = (k < 27) ? ((c * 4 + ky) * 132 + kx + off0) : 0;  // k>=27: B=0
    }
    __syncthreads();

    f32x4 acc[4][2];
#pragma unroll
    for (int mt = 0; mt < 4; ++mt)
#pragma unroll
        for (int nt = 0; nt < 2; ++nt) acc[mt][nt] = (f32x4){0.f, 0.f, 0.f, 0.f};

#pragma unroll
    for (int mt = 0; mt < 4; ++mt) {
        uint u[8];
#pragma unroll
        for (int e = 0; e < 8; ++e) u[e] = S[idx[e] + mt * 16];
        uint4 ahv, alv;
        uint* ah = (uint*)&ahv;
        uint* al = (uint*)&alv;
#pragma unroll
        for (int j = 0; j < 4; ++j) {
            ah[j] = (u[2 * j] & 0xffffu) | (u[2 * j + 1] << 16);
            al[j] = (u[2 * j] >> 16) | (u[2 * j + 1] & 0xffff0000u);
        }
        bf16x8 Ah = __builtin_bit_cast(bf16x8, ahv);
        bf16x8 Al = __builtin_bit_cast(bf16x8, alv);
        __builtin_amdgcn_s_setprio(1);
        acc[mt][0] = __builtin_amdgcn_mfma_f32_16x16x32_bf16(Ah, Bh0, acc[mt][0], 0, 0, 0);
        acc[mt][1] = __builtin_amdgcn_mfma_f32_16x16x32_bf16(Ah, Bh1, acc[mt][1], 0, 0, 0);
        acc[mt][0] = __builtin_amdgcn_mfma_f32_16x16x32_bf16(Ah, Bl0, acc[mt][0], 0, 0, 0);
        acc[mt][1] = __builtin_amdgcn_mfma_f32_16x16x32_bf16(Ah, Bl1, acc[mt][1], 0, 0, 0);
        acc[mt][0] = __builtin_amdgcn_mfma_f32_16x16x32_bf16(Al, Bh0, acc[mt][0], 0, 0, 0);
        acc[mt][1] = __builtin_amdgcn_mfma_f32_16x16x32_bf16(Al, Bh1, acc[mt][1], 0, 0, 0);
        __builtin_amdgcn_s_setprio(0);
    }

    // pool x-pairs in-lane (D rows q*4+r are conv x), then row-pairs via LDS
#pragma unroll
    for (int mt = 0; mt < 4; ++mt)
#pragma unroll
        for (int nt = 0; nt < 2; ++nt) {
            int oc = nt * 16 + n;
            int plx = mt * 8 + q * 2;
            pool[wsub][plx][oc]     = fmaxf(acc[mt][nt][0], acc[mt][nt][1]);
            pool[wsub][plx + 1][oc] = fmaxf(acc[mt][nt][2], acc[mt][nt][3]);
        }
    __syncthreads();
    {
        int plx = tid >> 2, ocq = tid & 3;       // plx in [0,64), oc = ocq*8..+8
        int wp = plx >> 5, pl = plx & 31;
        __attribute__((aligned(16))) ushort hb[8], lb[8];
#pragma unroll
        for (int e = 0; e < 8; ++e) {
            int oc = ocq * 8 + e;
            float v = fmaxf(pool[wp * 2][pl][oc], pool[wp * 2 + 1][pl][oc]);
            v = fmaxf(v + bias[oc], 0.f);
            ushort h = f2bf(v);
            hb[e] = h;
            lb[e] = f2bf(v - bf2f(h));
        }
        int ow = seg * 64 + plx;
        size_t base = (((size_t)((b * 256 + Y) * 256 + ow)) << 5) + ocq * 8;
        *(uint4*)(C1h + base) = *(const uint4*)hb;
        *(uint4*)(C1l + base) = *(const uint4*)lb;
    }
}

// ---------- Kernel B: conv2, ky-phase LDS-staged A + B, XOR-swizzled --------
__global__ __launch_bounds__(256) void conv2_mfma(
    const ushort* __restrict__ C1h, const ushort* __restrict__ C1l,
    const float* __restrict__ w2, const float* __restrict__ bias,
    ushort* __restrict__ Ahi, ushort* __restrict__ Alo, int stream_base)
{
    // A: [hl][rs][132 slots][32ch] ushort = 33792 B; B: 2x 3*2048 ushorts.
    __shared__ __attribute__((aligned(16))) char lds[58368];
    ushort* BhL = (ushort*)(lds + 33792);
    ushort* BlL = (ushort*)(lds + 46080);
    float (*pool)[32][65] = (float (*)[32][65])lds;  // padded (union after phases)

    const int seg = blockIdx.x, Y = blockIdx.y, b = blockIdx.z;
    const int tid = threadIdx.x, wsub = tid >> 6, lane = tid & 63;
    const int n = lane & 15, q = lane >> 4;
    const int rs = wsub & 1;               // wave conv-row select
    const int xs = wsub >> 1;              // wave x-half within block

    const uint4 zero4 = make_uint4(0u, 0u, 0u, 0u);
    // A-staging source swizzle: f for slot s_abs = 1 + j*16 + (lane>>2) is
    // ((s_abs)>>1)&3 = (((lane>>2)+1)>>1)&3  (j*16 term cancels mod 4).
    const int fA = (((lane >> 2) + 1) >> 1) & 3;
    const int laneSwz = (lane * 16) ^ (fA << 4);

    f32x4 acc[4][4];
#pragma unroll
    for (int mt = 0; mt < 4; ++mt)
#pragma unroll
        for (int nt = 0; nt < 4; ++nt) acc[mt][nt] = (f32x4){0.f, 0.f, 0.f, 0.f};

    for (int ky = 0; ky < 3; ++ky) {
        if (ky) __syncthreads();           // prior phase's LDS reads done

        // ---- stage A: wave (hl = wsub>>1, rsS = wsub&1) stages one row -----
        // LDS(s,c) holds global chunk c ^ f(s); achieved by swizzling the
        // per-lane GLOBAL source (dest stays linear, per m104/m173).
        {
            const int hl = wsub >> 1, rsS = wsub & 1;
            const int yy = 2 * Y + rsS + ky - 1;
            char* dstbase = lds + hl * 16896 + rsS * 8448 + 64;  // slots 1..128
            if (yy >= 0 && yy < 256) {
                const ushort* src = (hl ? C1l : C1h)
                    + ((size_t)(b * 256 + yy) * 256 + seg * 128) * 32;
                const char* s8 = (const char*)src + laneSwz;
#pragma unroll
                for (int j = 0; j < 8; ++j)
                    gl_lds16(s8 + j * 1024, dstbase + j * 1024);
            } else {
#pragma unroll
                for (int j = 0; j < 8; ++j)
                    *(uint4*)(dstbase + j * 1024 + lane * 16) = zero4;
            }
        }
        // ---- edge slots 0 (xp=seg*128-1) and 129 (xp=seg*128+128) ----------
        // f(0)=0 and f(129)=(129>>1)&3=0 -> plain (unswizzled) writes correct.
        if (tid < 32) {
            int combo = tid >> 3;          // hl*2 + rsE
            int hl = combo >> 1, rsE = combo & 1;
            int e = (tid >> 2) & 1, part = tid & 3;
            int yy = 2 * Y + rsE + ky - 1;
            int xp = seg * 128 + (e ? 128 : -1);
            uint4 v = zero4;
            if (yy >= 0 && yy < 256 && xp >= 0 && xp < 256) {
                const ushort* src = (hl ? C1l : C1h)
                    + ((size_t)(b * 256 + yy) * 256 + xp) * 32 + part * 8;
                v = *(const uint4*)src;
            }
            *(uint4*)(lds + hl * 16896 + rsE * 8448 + (e ? 129 * 64 : 0) + part * 16) = v;
        }
        // ---- stage B: taps ky*3 .. ky*3+2, swizzled write index ------------
        for (int i = tid; i < 6144; i += 256) {
            int t = ky * 3 + (i >> 11), r = i & 2047;
            float v = w2[r * 9 + t];
            ushort h = f2bf(v);
            int oc = r >> 5, kk = r & 31;
            int kks = kk ^ (((oc >> 1) & 3) << 3);
            int is = (i & ~2047) | (oc << 5) | kks;
            BhL[is] = h;
            BlL[is] = f2bf(v - bf2f(h));
        }
        __syncthreads();                   // drains vmcnt -> A landed; B visible

        for (int kx = 0; kx < 3; ++kx) {
            uint4 cH[4], cL[4];
#pragma unroll
            for (int mt = 0; mt < 4; ++mt) {
                int sidx = xs * 64 + mt * 16 + n + kx;
                int off = rs * 8448 + sidx * 64 + ((q ^ ((sidx >> 1) & 3)) << 4);
                cH[mt] = *(const uint4*)(lds + off);
                cL[mt] = *(const uint4*)(lds + 16896 + off);
            }
            bf16x8 bh[4], bl[4];
            const int fB = (n >> 1) & 3;   // == ((nt*16+n)>>1)&3 for all nt
#pragma unroll
            for (int nt = 0; nt < 4; ++nt) {
                int offB = kx * 4096 + (nt * 16 + n) * 64 + ((q ^ fB) << 4);
                bh[nt] = __builtin_bit_cast(bf16x8, *(const uint4*)((const char*)BhL + offB));
                bl[nt] = __builtin_bit_cast(bf16x8, *(const uint4*)((const char*)BlL + offB));
            }
            // step-outer MFMA order (dep distance 16), identical FP order
            __builtin_amdgcn_s_setprio(1);
#pragma unroll
            for (int mt = 0; mt < 4; ++mt) {
                bf16x8 ah = __builtin_bit_cast(bf16x8, cH[mt]);
#pragma unroll
                for (int nt = 0; nt < 4; ++nt)
                    acc[mt][nt] = __builtin_amdgcn_mfma_f32_16x16x32_bf16(ah, bh[nt], acc[mt][nt], 0, 0, 0);
            }
#pragma unroll
            for (int mt = 0; mt < 4; ++mt) {
                bf16x8 ah = __builtin_bit_cast(bf16x8, cH[mt]);
#pragma unroll
                for (int nt = 0; nt < 4; ++nt)
                    acc[mt][nt] = __builtin_amdgcn_mfma_f32_16x16x32_bf16(ah, bl[nt], acc[mt][nt], 0, 0, 0);
            }
#pragma unroll
            for (int mt = 0; mt < 4; ++mt) {
                bf16x8 al = __builtin_bit_cast(bf16x8, cL[mt]);
#pragma unroll
                for (int nt = 0; nt < 4; ++nt)
                    acc[mt][nt] = __builtin_amdgcn_mfma_f32_16x16x32_bf16(al, bh[nt], acc[mt][nt], 0, 0, 0);
            }
            __builtin_amdgcn_s_setprio(0);
        }
    }

    __syncthreads();   // all LDS reads done; safe to overwrite with pool

#pragma unroll
    for (int mt = 0; mt < 4; ++mt)
#pragma unroll
        for (int nt = 0; nt < 4; ++nt) {
            int oc = nt * 16 + n;
            int plx = mt * 8 + q * 2;
            pool[wsub][plx][oc]     = fmaxf(acc[mt][nt][0], acc[mt][nt][1]);
            pool[wsub][plx + 1][oc] = fmaxf(acc[mt][nt][2], acc[mt][nt][3]);
        }
    __syncthreads();

    {
        int plx = tid >> 2, ocq = tid & 3;
        int wp = plx >> 5, pl = plx & 31;
        __attribute__((aligned(16))) ushort hb[16], lb[16];
#pragma unroll
        for (int e = 0; e < 16; ++e) {
            int oc = ocq * 16 + e;
            float v = fmaxf(pool[wp * 2][pl][oc], pool[wp * 2 + 1][pl][oc]);
            v = fmaxf(v + bias[oc], 0.f);
            ushort h = f2bf(v);
            hb[e] = h;
            lb[e] = f2bf(v - bf2f(h));
        }
        int gx = seg * 64 + plx;
        int cpl = (stream_base >> 5) + (ocq >> 1);
        int cho = (ocq & 1) * 16;
        size_t base = (((size_t)(((b * 4 + cpl) * 128 + Y) * 128 + gx)) << 5) + cho;
        uint4* dh = (uint4*)(Ahi + base);
        uint4* dl = (uint4*)(Alo + base);
        dh[0] = *(const uint4*)&hb[0];
        dh[1] = *(const uint4*)&hb[8];
        dl[0] = *(const uint4*)&lb[0];
        dl[1] = *(const uint4*)&lb[8];
    }
}

// ---------- wprep: fuse_w fp32 -> fragment-ordered bf16 hi/lo ---------------
// CHUNK-MAJOR: Wf[c][t][oc][kk] = W[oc][ic=c*32+kk][ky=t/3][kx=t%3]
__global__ __launch_bounds__(256) void wprep(
    const float* __restrict__ fw, ushort* __restrict__ Whi,
    ushort* __restrict__ Wlo)
{
    int idx = blockIdx.x * 256 + threadIdx.x;
    if (idx >= 147456) return;
    int kk = idx & 31;
    int oc = (idx >> 5) & 127;
    int ct = idx >> 12;           // 0..35 = c*9 + t
    int c = ct / 9, t = ct - c * 9;
    int ic = c * 32 + kk;
    int ky = t / 3, kx = t - ky * 3;
    float v = fw[((oc * 128 + ic) * 3 + ky) * 3 + kx];
    ushort h = f2bf(v);
    Whi[idx] = h;
    Wlo[idx] = f2bf(v - bf2f(h));
}

// ---------- Kernel C: fuse conv via split-bf16 MFMA + relu + global mean ----
// R13/R14/R17 shape (256px x 128oc, wave = 64px x 128oc) + rolling 4-deep
// register prefetch of B. NO setprio (reg-ceiling kernel, R16 spill lesson).
__global__ __launch_bounds__(256, 2) void fuse_mfma(
    const ushort* __restrict__ Ahi, const ushort* __restrict__ Alo,
    const ushort* __restrict__ Whi, const ushort* __restrict__ Wlo,
    const float* __restrict__ bias, float* __restrict__ featsum)
{
    __shared__ float partial[4][128];
    const int b = blockIdx.x, ypair = blockIdx.y;
    const int tid = threadIdx.x, wsub = tid >> 6, lane = tid & 63;
    const int n = lane & 15, q = lane >> 4;
    const int y = ypair * 2 + (wsub >> 1);       // conv row for this wave
    const int xbase = (wsub & 1) * 64;           // wave covers x [xbase,xbase+64)

    f32x4 acc[4][8];
#pragma unroll
    for (int mt = 0; mt < 4; ++mt)
#pragma unroll
        for (int g = 0; g < 8; ++g) acc[mt][g] = (f32x4){0.f, 0.f, 0.f, 0.f};

    const uint4 zero4 = make_uint4(0u, 0u, 0u, 0u);

    auto loadA = [&](int tc, uint4* oh, uint4* ol) {
        int c = tc / 9, t = tc - c * 9;   // chunk-major decode
        int ky = t / 3, kx = t - ky * 3;
        int yy = y + ky - 1;
        bool yok = (yy >= 0) & (yy < 128);
#pragma unroll
        for (int mt = 0; mt < 4; ++mt) {
            int xp = xbase + mt * 16 + n + kx - 1;
            bool ok = yok & (xp >= 0) & (xp < 128);
            int yyc = ok ? yy : 0, xpc = ok ? xp : 0;
            size_t aoff = (((size_t)(((b * 4 + c) * 128 + yyc) * 128 + xpc)) << 5) + q * 8;
            oh[mt] = ok ? *(const uint4*)(Ahi + aoff) : zero4;
            ol[mt] = ok ? *(const uint4*)(Alo + aoff) : zero4;
        }
    };

    uint4 pAh[4], pAl[4];
    loadA(0, pAh, pAl);

    // lane-fixed B base; step address = base + s*512, s = tc*8+g
    const ushort* WhiB = Whi + n * 32 + q * 8;
    const ushort* WloB = Wlo + n * 32 + q * 8;

    // rolling 4-deep B prefetch buffer
    uint4 nBh[4], nBl[4];
#pragma unroll
    for (int j = 0; j < 4; ++j) {
        nBh[j] = *(const uint4*)(WhiB + j * 512);
        nBl[j] = *(const uint4*)(WloB + j * 512);
    }

    for (int tc = 0; tc < 36; ++tc) {
        uint4 cAh[4], cAl[4];
#pragma unroll
        for (int mt = 0; mt < 4; ++mt) { cAh[mt] = pAh[mt]; cAl[mt] = pAl[mt]; }
        if (tc + 1 < 36) loadA(tc + 1, pAh, pAl);
#pragma unroll
        for (int g = 0; g < 8; ++g) {
            const int slot = g & 3;
            bf16x8 bh = __builtin_bit_cast(bf16x8, nBh[slot]);
            bf16x8 bl = __builtin_bit_cast(bf16x8, nBl[slot]);
            // prefetch step s+4 (tail reads 4 padded never-consumed steps)
            {
                size_t off = (size_t)(tc * 8 + g + 4) * 512;
                nBh[slot] = *(const uint4*)(WhiB + off);
                nBl[slot] = *(const uint4*)(WloB + off);
            }
#pragma unroll
            for (int mt = 0; mt < 4; ++mt) {
                bf16x8 ah = __builtin_bit_cast(bf16x8, cAh[mt]);
                acc[mt][g] = __builtin_amdgcn_mfma_f32_16x16x32_bf16(ah, bh, acc[mt][g], 0, 0, 0);
            }
#pragma unroll
            for (int mt = 0; mt < 4; ++mt) {
                bf16x8 ah = __builtin_bit_cast(bf16x8, cAh[mt]);
                acc[mt][g] = __builtin_amdgcn_mfma_f32_16x16x32_bf16(ah, bl, acc[mt][g], 0, 0, 0);
            }
#pragma unroll
            for (int mt = 0; mt < 4; ++mt) {
                bf16x8 al = __builtin_bit_cast(bf16x8, cAl[mt]);
                acc[mt][g] = __builtin_amdgcn_mfma_f32_16x16x32_bf16(al, bh, acc[mt][g], 0, 0, 0);
            }
        }
    }

    // Epilogue: lane (q,n) of tile (mt,g) holds D[px = q*4+r][oc = g*16+n].
#pragma unroll
    for (int g = 0; g < 8; ++g) {
        float bv = bias[g * 16 + n];
        float v = 0.f;
#pragma unroll
        for (int mt = 0; mt < 4; ++mt)
#pragma unroll
            for (int r = 0; r < 4; ++r) v += fmaxf(acc[mt][g][r] + bv, 0.f);
        v += __shfl_xor(v, 16);
        v += __shfl_xor(v, 32);
        if (lane < 16) partial[wsub][g * 16 + lane] = v;
    }
    __syncthreads();
    if (tid < 128) {
        float v = partial[0][tid] + partial[1][tid] + partial[2][tid] + partial[3][tid];
        atomicAdd(&featsum[b * 128 + tid], v);
    }
}

// ---------- Kernel D: det head + sigmoid + NMS + outputs --------------------
__global__ void det_nms(const float* __restrict__ featsum,
                        const float* __restrict__ dw, const float* __restrict__ db,
                        float* __restrict__ out)
{
    const int b = threadIdx.x;
    if (b >= 8) return;
    const float inv = 1.0f / 16384.0f;

    float p[18];
    for (int j = 0; j < 18; ++j) {
        float a = db[j];
        const float* wp = &dw[j * 128];
        const float* f = &featsum[b * 128];
        for (int c = 0; c < 128; ++c) a = fmaf(wp[c], f[c] * inv, a);
        p[j] = a;
    }
    for (int a = 0; a < 3; ++a)
        for (int e = 0; e < 6; ++e) out[b * 18 + a * 6 + e] = p[a * 6 + e];

    float bx[3][4], sc[3];
    bool ck[3];
    for (int a = 0; a < 3; ++a) {
        for (int k = 0; k < 4; ++k) {
            bx[a][k] = p[a * 6 + k];
            out[144 + b * 12 + a * 4 + k] = bx[a][k];
        }
        float sg = 1.f / (1.f + expf(-p[a * 6 + 4]));
        sc[a] = sg;
        ck[a] = sg > 0.5f;
        out[240 + b * 3 + a] = sg;
    }

    float key[3];
    int order[3];
    bool used[3] = {false, false, false};
    for (int a = 0; a < 3; ++a) key[a] = ck[a] ? sc[a] : -INFINITY;
    for (int i = 0; i < 3; ++i) {
        int best = -1;
        float bk = 0.f;
        for (int a = 0; a < 3; ++a) {
            if (used[a]) continue;
            if (best < 0 || key[a] > bk) { best = a; bk = key[a]; }
        }
        order[i] = best;
        used[best] = true;
    }

    float X1[3], Y1[3], X2[3], Y2[3], AR[3];
    for (int i = 0; i < 3; ++i) {
        int o = order[i];
        X1[i] = bx[o][0]; Y1[i] = bx[o][1];
        X2[i] = bx[o][2]; Y2[i] = bx[o][3];
        AR[i] = (X2[i] - X1[i]) * (Y2[i] - Y1[i]);
    }
    bool suppressed[3] = {false, false, false}, keep_s[3];
    for (int i = 0; i < 3; ++i) {
        bool valid = !suppressed[i];
        keep_s[i] = valid;
        if (valid) {
            for (int j = i + 1; j < 3; ++j) {
                float ix1 = fmaxf(X1[i], X1[j]), iy1 = fmaxf(Y1[i], Y1[j]);
                float ix2 = fminf(X2[i], X2[j]), iy2 = fminf(Y2[i], Y2[j]);
                float inter = fmaxf(ix2 - ix1, 0.f) * fmaxf(iy2 - iy1, 0.f);
                float iou = inter / (AR[i] + AR[j] - inter);
                if (iou > 0.5f) suppressed[j] = true;
            }
        }
    }
    bool keep[3];
    for (int i = 0; i < 3; ++i) keep[order[i]] = keep_s[i];
    for (int a = 0; a < 3; ++a)
        out[264 + b * 3 + a] = (keep[a] && ck[a]) ? 1.f : 0.f;
}

__global__ void zero_feat(float* __restrict__ p)
{
    int i = blockIdx.x * 256 + threadIdx.x;
    if (i < 1024) p[i] = 0.f;
}

// ---------------------------------------------------------------------------
extern "C" void kernel_launch(void* const* d_in, const int* in_sizes, int n_in,
                              void* d_out, int out_size, void* d_ws, size_t ws_size,
                              hipStream_t stream)
{
    const float* x      = (const float*)d_in[0];
    const float* rgb_w1 = (const float*)d_in[1];
    const float* rgb_b1 = (const float*)d_in[2];
    const float* rgb_w2 = (const float*)d_in[3];
    const float* rgb_b2 = (const float*)d_in[4];
    const float* ir_w1  = (const float*)d_in[5];
    const float* ir_b1  = (const float*)d_in[6];
    const float* ir_w2  = (const float*)d_in[7];
    const float* ir_b2  = (const float*)d_in[8];
    const float* fuse_w = (const float*)d_in[9];
    const float* fuse_b = (const float*)d_in[10];
    const float* det_w  = (const float*)d_in[11];
    const float* det_b  = (const float*)d_in[12];
    float* out = (float*)d_out;

    char* ws = (char*)d_ws;
    ushort* C1h  = (ushort*)(ws);                         // 33,554,432 B
    ushort* C1l  = (ushort*)(ws + 33554432);              // 33,554,432 B
    // post-conv2 reuse of the C1 region:
    ushort* Whi  = (ushort*)(ws);                         // 294,912 B
    ushort* Wlo  = (ushort*)(ws + 299008);                // 294,912 B
    float*  feat = (float*)(ws + 598016);                 // 4,096 B
    ushort* Ahi  = (ushort*)(ws + 67108864);              // 33,554,432 B
    ushort* Alo  = (ushort*)(ws + 100663296);             // 33,554,432 B
    // W1p (8 KB) parked in the TAIL of Alo: bytes [134209536, 134217728).
    // Written ONLY by conv2_mfma(ir) (plane b=7,cpl=3), after both
    // conv1_mfma dispatches have consumed W1p.
    uint*   W1p  = (uint*)(ws + 134209536);

    dim3 blk(256);
    hipLaunchKernelGGL(w1prep, dim3(8), blk, 0, stream, rgb_w1, ir_w1, W1p);
    hipLaunchKernelGGL(conv1_mfma, dim3(4, 256, 8), blk, 0, stream, x, W1p, rgb_b1, C1h, C1l);
    hipLaunchKernelGGL(conv2_mfma, dim3(2, 128, 8), blk, 0, stream, C1h, C1l, rgb_w2, rgb_b2, Ahi, Alo, 0);
    hipLaunchKernelGGL(conv1_mfma, dim3(4, 256, 8), blk, 0, stream, x, W1p + 1024, ir_b1, C1h, C1l);
    hipLaunchKernelGGL(conv2_mfma, dim3(2, 128, 8), blk, 0, stream, C1h, C1l, ir_w2, ir_b2, Ahi, Alo, 64);
    hipLaunchKernelGGL(wprep, dim3(576), blk, 0, stream, fuse_w, Whi, Wlo);
    hipLaunchKernelGGL(zero_feat, dim3(4), blk, 0, stream, feat);
    hipLaunchKernelGGL(fuse_mfma, dim3(8, 64), blk, 0, stream, Ahi, Alo, Whi, Wlo, fuse_b, feat);
    hipLaunchKernelGGL(det_nms, dim3(1), dim3(64), 0, stream, feat, det_w, det_b, out);
}

// Round 8
// 499.836 us; speedup vs baseline: 1.4025x; 1.0397x over previous
//
#include <hip/hip_runtime.h>
#include <math.h>

// ---------------------------------------------------------------------------
// MultiStreamCNN. R21: restore R18 (best measured, 494.8us) and apply ONLY
// evidence-backed deltas: (1) conv2 = byte-exact R18 (R20's swizzles hurt
// -25us: conflict theory was transplanted from R19-fuse counters, never
// measured on conv2; swizzle VALU + permuted gl_lds source cost real time);
// (2) pool pads conv1 [32][33] / conv2 [32][65] -- targets conv1's measured
// 3.0M SQ_LDS_BANK_CONFLICT (stride-32 epilogue, bank independent of q);
// (3) zero_feat folded into wprep (same post-conv2 ordering point; feat
// overlaps C1h so it cannot run earlier) -> one fewer dispatch.
// fuse = R17/R18 byte-exact (122us plateau, no setprio: R16 spill lesson).
// ---------------------------------------------------------------------------

typedef __bf16 bf16x8 __attribute__((ext_vector_type(8)));
typedef float f32x4 __attribute__((ext_vector_type(4)));

static __device__ __forceinline__ ushort f2bf(float f) {
    unsigned u = __float_as_uint(f);
    unsigned r = (u + 0x7fffu + ((u >> 16) & 1u)) >> 16;   // RNE
    return (ushort)r;
}
static __device__ __forceinline__ float bf2f(ushort h) {
    return __uint_as_float(((unsigned)h) << 16);
}
static __device__ __forceinline__ void gl_lds16(const void* g, void* l) {
    __builtin_amdgcn_global_load_lds(
        (const __attribute__((address_space(1))) void*)g,
        (__attribute__((address_space(3))) void*)l, 16, 0, 0);
}

// ---------- w1prep: conv1 weights (both streams) -> packed hi|lo ------------
// W1p[s][oc][k] : k = c*9 + ky*3 + kx for k<27, zero-padded to 32.
__global__ __launch_bounds__(256) void w1prep(
    const float* __restrict__ w_rgb, const float* __restrict__ w_ir,
    uint* __restrict__ W1p)
{
    int i = blockIdx.x * 256 + threadIdx.x;
    if (i >= 2048) return;
    int s = i >> 10, r = i & 1023;
    int oc = r >> 5, k = r & 31;
    const float* w = s ? w_ir : w_rgb;
    float v = (k < 27) ? w[oc * 27 + k] : 0.f;   // [oc][c][ky][kx] linear == oc*27+k
    ushort h = f2bf(v);
    W1p[i] = (uint)h | ((uint)f2bf(v - bf2f(h)) << 16);
}

// ---------- Kernel A: conv3x3 (3->32) via MFMA + bias + relu + maxpool2 -----
__global__ __launch_bounds__(256) void conv1_mfma(
    const float* __restrict__ x, const uint* __restrict__ W1p,
    const float* __restrict__ bias, ushort* __restrict__ C1h,
    ushort* __restrict__ C1l)
{
    __shared__ uint S[3 * 4 * 132];          // packed hi|lo x tile, 6336 B
    __shared__ float pool[4][32][33];        // stride 33: bank depends on plx -> no 16-way

    const int seg = blockIdx.x, Y = blockIdx.y, b = blockIdx.z;
    const int tid = threadIdx.x, wsub = tid >> 6, lane = tid & 63;
    const int n = lane & 15, q = lane >> 4;

    // B fragments from global packed W1p (4KB, L2-hot): oc = nt*16+n, k = q*8+e
    uint4 bu0a = *(const uint4*)&W1p[n * 32 + q * 8];
    uint4 bu0b = *(const uint4*)&W1p[n * 32 + q * 8 + 4];
    uint4 bu1a = *(const uint4*)&W1p[(16 + n) * 32 + q * 8];
    uint4 bu1b = *(const uint4*)&W1p[(16 + n) * 32 + q * 8 + 4];

    // stage x rows 2Y-1..2Y+2, cols seg*128-1..+128 (130 used, stride 132)
    const int ih0 = 2 * Y - 1, iw0 = seg * 128 - 1;
    for (int i = tid; i < 1584; i += 256) {
        int c = i / 528, rem = i - c * 528;
        int r = rem / 132, cc = rem - r * 132;
        int ih = ih0 + r, iw = iw0 + cc;
        float v = 0.f;
        if (cc < 130 && ih >= 0 && ih < 512 && iw >= 0 && iw < 512)
            v = x[((b * 3 + c) * 512 + ih) * 512 + iw];
        ushort h = f2bf(v);
        S[i] = (uint)h | ((uint)f2bf(v - bf2f(h)) << 16);
    }

    // unpack B into bf16x8 fragments (hi from low16, lo from high16)
    uint4 bh0v, bl0v, bh1v, bl1v;
    {
        uint u0[8], u1[8];
        *(uint4*)&u0[0] = bu0a; *(uint4*)&u0[4] = bu0b;
        *(uint4*)&u1[0] = bu1a; *(uint4*)&u1[4] = bu1b;
        uint* bh0 = (uint*)&bh0v; uint* bl0 = (uint*)&bl0v;
        uint* bh1 = (uint*)&bh1v; uint* bl1 = (uint*)&bl1v;
#pragma unroll
        for (int j = 0; j < 4; ++j) {
            bh0[j] = (u0[2 * j] & 0xffffu) | (u0[2 * j + 1] << 16);
            bl0[j] = (u0[2 * j] >> 16) | (u0[2 * j + 1] & 0xffff0000u);
            bh1[j] = (u1[2 * j] & 0xffffu) | (u1[2 * j + 1] << 16);
            bl1[j] = (u1[2 * j] >> 16) | (u1[2 * j + 1] & 0xffff0000u);
        }
    }
    bf16x8 Bh0 = __builtin_bit_cast(bf16x8, bh0v);
    bf16x8 Bl0 = __builtin_bit_cast(bf16x8, bl0v);
    bf16x8 Bh1 = __builtin_bit_cast(bf16x8, bh1v);
    bf16x8 Bl1 = __builtin_bit_cast(bf16x8, bl1v);

    // per-lane gather offsets: k = q*8+e -> (c,ky,kx)
    int idx[8];
    const int off0 = (wsub & 1) * 132 + (wsub >> 1) * 64 + n;
#pragma unroll
    for (int e = 0; e < 8; ++e) {
        int k = q * 8 + e;
        int c = (k >= 18) ? ((k >= 27) ? 3 : 2) : ((k >= 9) ? 1 : 0);
        int t = k - c * 9;
        int ky = (t >= 6) ? 2 : ((t >= 3) ? 1 : 0);
        int kx = t - ky * 3;
        idx[e] = (k < 27) ? ((c * 4 + ky) * 132 + kx + off0) : 0;  // k>=27: B=0
    }
    __syncthreads();

    f32x4 acc[4][2];
#pragma unroll
    for (int mt = 0; mt < 4; ++mt)
#pragma unroll
        for (int nt = 0; nt < 2; ++nt) acc[mt][nt] = (f32x4){0.f, 0.f, 0.f, 0.f};

#pragma unroll
    for (int mt = 0; mt < 4; ++mt) {
        uint u[8];
#pragma unroll
        for (int e = 0; e < 8; ++e) u[e] = S[idx[e] + mt * 16];
        uint4 ahv, alv;
        uint* ah = (uint*)&ahv;
        uint* al = (uint*)&alv;
#pragma unroll
        for (int j = 0; j < 4; ++j) {
            ah[j] = (u[2 * j] & 0xffffu) | (u[2 * j + 1] << 16);
            al[j] = (u[2 * j] >> 16) | (u[2 * j + 1] & 0xffff0000u);
        }
        bf16x8 Ah = __builtin_bit_cast(bf16x8, ahv);
        bf16x8 Al = __builtin_bit_cast(bf16x8, alv);
        __builtin_amdgcn_s_setprio(1);
        acc[mt][0] = __builtin_amdgcn_mfma_f32_16x16x32_bf16(Ah, Bh0, acc[mt][0], 0, 0, 0);
        acc[mt][1] = __builtin_amdgcn_mfma_f32_16x16x32_bf16(Ah, Bh1, acc[mt][1], 0, 0, 0);
        acc[mt][0] = __builtin_amdgcn_mfma_f32_16x16x32_bf16(Ah, Bl0, acc[mt][0], 0, 0, 0);
        acc[mt][1] = __builtin_amdgcn_mfma_f32_16x16x32_bf16(Ah, Bl1, acc[mt][1], 0, 0, 0);
        acc[mt][0] = __builtin_amdgcn_mfma_f32_16x16x32_bf16(Al, Bh0, acc[mt][0], 0, 0, 0);
        acc[mt][1] = __builtin_amdgcn_mfma_f32_16x16x32_bf16(Al, Bh1, acc[mt][1], 0, 0, 0);
        __builtin_amdgcn_s_setprio(0);
    }

    // pool x-pairs in-lane (D rows q*4+r are conv x), then row-pairs via LDS
#pragma unroll
    for (int mt = 0; mt < 4; ++mt)
#pragma unroll
        for (int nt = 0; nt < 2; ++nt) {
            int oc = nt * 16 + n;
            int plx = mt * 8 + q * 2;
            pool[wsub][plx][oc]     = fmaxf(acc[mt][nt][0], acc[mt][nt][1]);
            pool[wsub][plx + 1][oc] = fmaxf(acc[mt][nt][2], acc[mt][nt][3]);
        }
    __syncthreads();
    {
        int plx = tid >> 2, ocq = tid & 3;       // plx in [0,64), oc = ocq*8..+8
        int wp = plx >> 5, pl = plx & 31;
        __attribute__((aligned(16))) ushort hb[8], lb[8];
#pragma unroll
        for (int e = 0; e < 8; ++e) {
            int oc = ocq * 8 + e;
            float v = fmaxf(pool[wp * 2][pl][oc], pool[wp * 2 + 1][pl][oc]);
            v = fmaxf(v + bias[oc], 0.f);
            ushort h = f2bf(v);
            hb[e] = h;
            lb[e] = f2bf(v - bf2f(h));
        }
        int ow = seg * 64 + plx;
        size_t base = (((size_t)((b * 256 + Y) * 256 + ow)) << 5) + ocq * 8;
        *(uint4*)(C1h + base) = *(const uint4*)hb;
        *(uint4*)(C1l + base) = *(const uint4*)lb;
    }
}

// ---------- Kernel B: conv2, ky-phase LDS-staged A + B (R18 form) -----------
// Block: 2 conv rows (2Y, 2Y+1) x 128 px (seg). Wave: rs=wsub&1 row,
// xs=wsub>>1 x-half. Per phase ky: stage rows {2Y+ky-1, 2Y+ky} (hi+lo) +
// taps ky*3..+2 of B; compute kx=0..2 from LDS.
__global__ __launch_bounds__(256) void conv2_mfma(
    const ushort* __restrict__ C1h, const ushort* __restrict__ C1l,
    const float* __restrict__ w2, const float* __restrict__ bias,
    ushort* __restrict__ Ahi, ushort* __restrict__ Alo, int stream_base)
{
    // A: [hl][rs][132 slots][32ch] ushort = 33792 B; B: 2x 3*2048 ushorts.
    __shared__ __attribute__((aligned(16))) char lds[58368];
    ushort* BhL = (ushort*)(lds + 33792);
    ushort* BlL = (ushort*)(lds + 46080);
    float (*pool)[32][65] = (float (*)[32][65])lds;  // padded stride 65 (union after phases)

    const int seg = blockIdx.x, Y = blockIdx.y, b = blockIdx.z;
    const int tid = threadIdx.x, wsub = tid >> 6, lane = tid & 63;
    const int n = lane & 15, q = lane >> 4;
    const int rs = wsub & 1;               // wave conv-row select
    const int xs = wsub >> 1;              // wave x-half within block

    const uint4 zero4 = make_uint4(0u, 0u, 0u, 0u);

    f32x4 acc[4][4];
#pragma unroll
    for (int mt = 0; mt < 4; ++mt)
#pragma unroll
        for (int nt = 0; nt < 4; ++nt) acc[mt][nt] = (f32x4){0.f, 0.f, 0.f, 0.f};

    for (int ky = 0; ky < 3; ++ky) {
        if (ky) __syncthreads();           // prior phase's LDS reads done

        // ---- stage A: wave (hl = wsub>>1, rsS = wsub&1) stages one row -----
        {
            const int hl = wsub >> 1, rsS = wsub & 1;
            const int yy = 2 * Y + rsS + ky - 1;
            char* dstbase = lds + hl * 16896 + rsS * 8448 + 64;  // slots 1..128
            if (yy >= 0 && yy < 256) {
                const ushort* src = (hl ? C1l : C1h)
                    + ((size_t)(b * 256 + yy) * 256 + seg * 128) * 32;
                const char* s8 = (const char*)src + lane * 16;
#pragma unroll
                for (int j = 0; j < 8; ++j)
                    gl_lds16(s8 + j * 1024, dstbase + j * 1024);
            } else {
#pragma unroll
                for (int j = 0; j < 8; ++j)
                    *(uint4*)(dstbase + j * 1024 + lane * 16) = zero4;
            }
        }
        // ---- edge slots 0 (xp=seg*128-1) and 129 (xp=seg*128+128) ----------
        if (tid < 32) {
            int combo = tid >> 3;          // hl*2 + rsE
            int hl = combo >> 1, rsE = combo & 1;
            int e = (tid >> 2) & 1, part = tid & 3;
            int yy = 2 * Y + rsE + ky - 1;
            int xp = seg * 128 + (e ? 128 : -1);
            uint4 v = zero4;
            if (yy >= 0 && yy < 256 && xp >= 0 && xp < 256) {
                const ushort* src = (hl ? C1l : C1h)
                    + ((size_t)(b * 256 + yy) * 256 + xp) * 32 + part * 8;
                v = *(const uint4*)src;
            }
            *(uint4*)(lds + hl * 16896 + rsE * 8448 + (e ? 129 * 64 : 0) + part * 16) = v;
        }
        // ---- stage B: taps ky*3 .. ky*3+2 ---------------------------------
        for (int i = tid; i < 6144; i += 256) {
            int t = ky * 3 + (i >> 11), r = i & 2047;
            float v = w2[r * 9 + t];
            ushort h = f2bf(v);
            BhL[i] = h;
            BlL[i] = f2bf(v - bf2f(h));
        }
        __syncthreads();                   // drains vmcnt -> A landed; B visible

        for (int kx = 0; kx < 3; ++kx) {
            uint4 cH[4], cL[4];
#pragma unroll
            for (int mt = 0; mt < 4; ++mt) {
                int off = rs * 8448 + (xs * 64 + mt * 16 + n + kx) * 64 + q * 16;
                cH[mt] = *(const uint4*)(lds + off);
                cL[mt] = *(const uint4*)(lds + 16896 + off);
            }
            bf16x8 bh[4], bl[4];
#pragma unroll
            for (int nt = 0; nt < 4; ++nt) {
                int off = kx * 2048 + (nt * 16 + n) * 32 + q * 8;
                bh[nt] = __builtin_bit_cast(bf16x8, *(const uint4*)&BhL[off]);
                bl[nt] = __builtin_bit_cast(bf16x8, *(const uint4*)&BlL[off]);
            }
            // step-outer MFMA order (dep distance 16), identical FP order
            __builtin_amdgcn_s_setprio(1);
#pragma unroll
            for (int mt = 0; mt < 4; ++mt) {
                bf16x8 ah = __builtin_bit_cast(bf16x8, cH[mt]);
#pragma unroll
                for (int nt = 0; nt < 4; ++nt)
                    acc[mt][nt] = __builtin_amdgcn_mfma_f32_16x16x32_bf16(ah, bh[nt], acc[mt][nt], 0, 0, 0);
            }
#pragma unroll
            for (int mt = 0; mt < 4; ++mt) {
                bf16x8 ah = __builtin_bit_cast(bf16x8, cH[mt]);
#pragma unroll
                for (int nt = 0; nt < 4; ++nt)
                    acc[mt][nt] = __builtin_amdgcn_mfma_f32_16x16x32_bf16(ah, bl[nt], acc[mt][nt], 0, 0, 0);
            }
#pragma unroll
            for (int mt = 0; mt < 4; ++mt) {
                bf16x8 al = __builtin_bit_cast(bf16x8, cL[mt]);
#pragma unroll
                for (int nt = 0; nt < 4; ++nt)
                    acc[mt][nt] = __builtin_amdgcn_mfma_f32_16x16x32_bf16(al, bh[nt], acc[mt][nt], 0, 0, 0);
            }
            __builtin_amdgcn_s_setprio(0);
        }
    }

    __syncthreads();   // all LDS reads done; safe to overwrite with pool

#pragma unroll
    for (int mt = 0; mt < 4; ++mt)
#pragma unroll
        for (int nt = 0; nt < 4; ++nt) {
            int oc = nt * 16 + n;
            int plx = mt * 8 + q * 2;
            pool[wsub][plx][oc]     = fmaxf(acc[mt][nt][0], acc[mt][nt][1]);
            pool[wsub][plx + 1][oc] = fmaxf(acc[mt][nt][2], acc[mt][nt][3]);
        }
    __syncthreads();

    {
        int plx = tid >> 2, ocq = tid & 3;
        int wp = plx >> 5, pl = plx & 31;
        __attribute__((aligned(16))) ushort hb[16], lb[16];
#pragma unroll
        for (int e = 0; e < 16; ++e) {
            int oc = ocq * 16 + e;
            float v = fmaxf(pool[wp * 2][pl][oc], pool[wp * 2 + 1][pl][oc]);
            v = fmaxf(v + bias[oc], 0.f);
            ushort h = f2bf(v);
            hb[e] = h;
            lb[e] = f2bf(v - bf2f(h));
        }
        int gx = seg * 64 + plx;
        int cpl = (stream_base >> 5) + (ocq >> 1);
        int cho = (ocq & 1) * 16;
        size_t base = (((size_t)(((b * 4 + cpl) * 128 + Y) * 128 + gx)) << 5) + cho;
        uint4* dh = (uint4*)(Ahi + base);
        uint4* dl = (uint4*)(Alo + base);
        dh[0] = *(const uint4*)&hb[0];
        dh[1] = *(const uint4*)&hb[8];
        dl[0] = *(const uint4*)&lb[0];
        dl[1] = *(const uint4*)&lb[8];
    }
}

// ---------- wprep: fuse_w fp32 -> fragment-ordered bf16 hi/lo + feat zero ---
// CHUNK-MAJOR: Wf[c][t][oc][kk] = W[oc][ic=c*32+kk][ky=t/3][kx=t%3].
// Also zeroes featsum (runs at the same post-conv2 point zero_feat did;
// feat overlaps the C1h region so it cannot be zeroed earlier).
__global__ __launch_bounds__(256) void wprep(
    const float* __restrict__ fw, ushort* __restrict__ Whi,
    ushort* __restrict__ Wlo, float* __restrict__ feat)
{
    int idx = blockIdx.x * 256 + threadIdx.x;
    if (idx < 1024) feat[idx] = 0.f;
    if (idx >= 147456) return;
    int kk = idx & 31;
    int oc = (idx >> 5) & 127;
    int ct = idx >> 12;           // 0..35 = c*9 + t
    int c = ct / 9, t = ct - c * 9;
    int ic = c * 32 + kk;
    int ky = t / 3, kx = t - ky * 3;
    float v = fw[((oc * 128 + ic) * 3 + ky) * 3 + kx];
    ushort h = f2bf(v);
    Whi[idx] = h;
    Wlo[idx] = f2bf(v - bf2f(h));
}

// ---------- Kernel C: fuse conv via split-bf16 MFMA + relu + global mean ----
// R13/R14/R17/R18 shape (256px x 128oc, wave = 64px x 128oc) + rolling
// 4-deep register prefetch of B. NO setprio (reg-ceiling, R16 spill lesson).
__global__ __launch_bounds__(256, 2) void fuse_mfma(
    const ushort* __restrict__ Ahi, const ushort* __restrict__ Alo,
    const ushort* __restrict__ Whi, const ushort* __restrict__ Wlo,
    const float* __restrict__ bias, float* __restrict__ featsum)
{
    __shared__ float partial[4][128];
    const int b = blockIdx.x, ypair = blockIdx.y;
    const int tid = threadIdx.x, wsub = tid >> 6, lane = tid & 63;
    const int n = lane & 15, q = lane >> 4;
    const int y = ypair * 2 + (wsub >> 1);       // conv row for this wave
    const int xbase = (wsub & 1) * 64;           // wave covers x [xbase,xbase+64)

    f32x4 acc[4][8];
#pragma unroll
    for (int mt = 0; mt < 4; ++mt)
#pragma unroll
        for (int g = 0; g < 8; ++g) acc[mt][g] = (f32x4){0.f, 0.f, 0.f, 0.f};

    const uint4 zero4 = make_uint4(0u, 0u, 0u, 0u);

    auto loadA = [&](int tc, uint4* oh, uint4* ol) {
        int c = tc / 9, t = tc - c * 9;   // chunk-major decode
        int ky = t / 3, kx = t - ky * 3;
        int yy = y + ky - 1;
        bool yok = (yy >= 0) & (yy < 128);
#pragma unroll
        for (int mt = 0; mt < 4; ++mt) {
            int xp = xbase + mt * 16 + n + kx - 1;
            bool ok = yok & (xp >= 0) & (xp < 128);
            int yyc = ok ? yy : 0, xpc = ok ? xp : 0;
            size_t aoff = (((size_t)(((b * 4 + c) * 128 + yyc) * 128 + xpc)) << 5) + q * 8;
            oh[mt] = ok ? *(const uint4*)(Ahi + aoff) : zero4;
            ol[mt] = ok ? *(const uint4*)(Alo + aoff) : zero4;
        }
    };

    uint4 pAh[4], pAl[4];
    loadA(0, pAh, pAl);

    // lane-fixed B base; step address = base + s*512, s = tc*8+g
    const ushort* WhiB = Whi + n * 32 + q * 8;
    const ushort* WloB = Wlo + n * 32 + q * 8;

    // rolling 4-deep B prefetch buffer
    uint4 nBh[4], nBl[4];
#pragma unroll
    for (int j = 0; j < 4; ++j) {
        nBh[j] = *(const uint4*)(WhiB + j * 512);
        nBl[j] = *(const uint4*)(WloB + j * 512);
    }

    for (int tc = 0; tc < 36; ++tc) {
        uint4 cAh[4], cAl[4];
#pragma unroll
        for (int mt = 0; mt < 4; ++mt) { cAh[mt] = pAh[mt]; cAl[mt] = pAl[mt]; }
        if (tc + 1 < 36) loadA(tc + 1, pAh, pAl);
#pragma unroll
        for (int g = 0; g < 8; ++g) {
            const int slot = g & 3;
            bf16x8 bh = __builtin_bit_cast(bf16x8, nBh[slot]);
            bf16x8 bl = __builtin_bit_cast(bf16x8, nBl[slot]);
            // prefetch step s+4 (tail reads 4 padded never-consumed steps)
            {
                size_t off = (size_t)(tc * 8 + g + 4) * 512;
                nBh[slot] = *(const uint4*)(WhiB + off);
                nBl[slot] = *(const uint4*)(WloB + off);
            }
#pragma unroll
            for (int mt = 0; mt < 4; ++mt) {
                bf16x8 ah = __builtin_bit_cast(bf16x8, cAh[mt]);
                acc[mt][g] = __builtin_amdgcn_mfma_f32_16x16x32_bf16(ah, bh, acc[mt][g], 0, 0, 0);
            }
#pragma unroll
            for (int mt = 0; mt < 4; ++mt) {
                bf16x8 ah = __builtin_bit_cast(bf16x8, cAh[mt]);
                acc[mt][g] = __builtin_amdgcn_mfma_f32_16x16x32_bf16(ah, bl, acc[mt][g], 0, 0, 0);
            }
#pragma unroll
            for (int mt = 0; mt < 4; ++mt) {
                bf16x8 al = __builtin_bit_cast(bf16x8, cAl[mt]);
                acc[mt][g] = __builtin_amdgcn_mfma_f32_16x16x32_bf16(al, bh, acc[mt][g], 0, 0, 0);
            }
        }
    }

    // Epilogue: lane (q,n) of tile (mt,g) holds D[px = q*4+r][oc = g*16+n].
#pragma unroll
    for (int g = 0; g < 8; ++g) {
        float bv = bias[g * 16 + n];
        float v = 0.f;
#pragma unroll
        for (int mt = 0; mt < 4; ++mt)
#pragma unroll
            for (int r = 0; r < 4; ++r) v += fmaxf(acc[mt][g][r] + bv, 0.f);
        v += __shfl_xor(v, 16);
        v += __shfl_xor(v, 32);
        if (lane < 16) partial[wsub][g * 16 + lane] = v;
    }
    __syncthreads();
    if (tid < 128) {
        float v = partial[0][tid] + partial[1][tid] + partial[2][tid] + partial[3][tid];
        atomicAdd(&featsum[b * 128 + tid], v);
    }
}

// ---------- Kernel D: det head + sigmoid + NMS + outputs --------------------
__global__ void det_nms(const float* __restrict__ featsum,
                        const float* __restrict__ dw, const float* __restrict__ db,
                        float* __restrict__ out)
{
    const int b = threadIdx.x;
    if (b >= 8) return;
    const float inv = 1.0f / 16384.0f;

    float p[18];
    for (int j = 0; j < 18; ++j) {
        float a = db[j];
        const float* wp = &dw[j * 128];
        const float* f = &featsum[b * 128];
        for (int c = 0; c < 128; ++c) a = fmaf(wp[c], f[c] * inv, a);
        p[j] = a;
    }
    for (int a = 0; a < 3; ++a)
        for (int e = 0; e < 6; ++e) out[b * 18 + a * 6 + e] = p[a * 6 + e];

    float bx[3][4], sc[3];
    bool ck[3];
    for (int a = 0; a < 3; ++a) {
        for (int k = 0; k < 4; ++k) {
            bx[a][k] = p[a * 6 + k];
            out[144 + b * 12 + a * 4 + k] = bx[a][k];
        }
        float sg = 1.f / (1.f + expf(-p[a * 6 + 4]));
        sc[a] = sg;
        ck[a] = sg > 0.5f;
        out[240 + b * 3 + a] = sg;
    }

    float key[3];
    int order[3];
    bool used[3] = {false, false, false};
    for (int a = 0; a < 3; ++a) key[a] = ck[a] ? sc[a] : -INFINITY;
    for (int i = 0; i < 3; ++i) {
        int best = -1;
        float bk = 0.f;
        for (int a = 0; a < 3; ++a) {
            if (used[a]) continue;
            if (best < 0 || key[a] > bk) { best = a; bk = key[a]; }
        }
        order[i] = best;
        used[best] = true;
    }

    float X1[3], Y1[3], X2[3], Y2[3], AR[3];
    for (int i = 0; i < 3; ++i) {
        int o = order[i];
        X1[i] = bx[o][0]; Y1[i] = bx[o][1];
        X2[i] = bx[o][2]; Y2[i] = bx[o][3];
        AR[i] = (X2[i] - X1[i]) * (Y2[i] - Y1[i]);
    }
    bool suppressed[3] = {false, false, false}, keep_s[3];
    for (int i = 0; i < 3; ++i) {
        bool valid = !suppressed[i];
        keep_s[i] = valid;
        if (valid) {
            for (int j = i + 1; j < 3; ++j) {
                float ix1 = fmaxf(X1[i], X1[j]), iy1 = fmaxf(Y1[i], Y1[j]);
                float ix2 = fminf(X2[i], X2[j]), iy2 = fminf(Y2[i], Y2[j]);
                float inter = fmaxf(ix2 - ix1, 0.f) * fmaxf(iy2 - iy1, 0.f);
                float iou = inter / (AR[i] + AR[j] - inter);
                if (iou > 0.5f) suppressed[j] = true;
            }
        }
    }
    bool keep[3];
    for (int i = 0; i < 3; ++i) keep[order[i]] = keep_s[i];
    for (int a = 0; a < 3; ++a)
        out[264 + b * 3 + a] = (keep[a] && ck[a]) ? 1.f : 0.f;
}

// ---------------------------------------------------------------------------
extern "C" void kernel_launch(void* const* d_in, const int* in_sizes, int n_in,
                              void* d_out, int out_size, void* d_ws, size_t ws_size,
                              hipStream_t stream)
{
    const float* x      = (const float*)d_in[0];
    const float* rgb_w1 = (const float*)d_in[1];
    const float* rgb_b1 = (const float*)d_in[2];
    const float* rgb_w2 = (const float*)d_in[3];
    const float* rgb_b2 = (const float*)d_in[4];
    const float* ir_w1  = (const float*)d_in[5];
    const float* ir_b1  = (const float*)d_in[6];
    const float* ir_w2  = (const float*)d_in[7];
    const float* ir_b2  = (const float*)d_in[8];
    const float* fuse_w = (const float*)d_in[9];
    const float* fuse_b = (const float*)d_in[10];
    const float* det_w  = (const float*)d_in[11];
    const float* det_b  = (const float*)d_in[12];
    float* out = (float*)d_out;

    char* ws = (char*)d_ws;
    ushort* C1h  = (ushort*)(ws);                         // 33,554,432 B
    ushort* C1l  = (ushort*)(ws + 33554432);              // 33,554,432 B
    // post-conv2 reuse of the C1 region:
    ushort* Whi  = (ushort*)(ws);                         // 294,912 B
    ushort* Wlo  = (ushort*)(ws + 299008);                // 294,912 B
    float*  feat = (float*)(ws + 598016);                 // 4,096 B
    ushort* Ahi  = (ushort*)(ws + 67108864);              // 33,554,432 B
    ushort* Alo  = (ushort*)(ws + 100663296);             // 33,554,432 B
    // W1p (8 KB) parked in the TAIL of Alo: bytes [134209536, 134217728).
    // Written ONLY by conv2_mfma(ir) (plane b=7,cpl=3), after both
    // conv1_mfma dispatches have consumed W1p.
    uint*   W1p  = (uint*)(ws + 134209536);

    dim3 blk(256);
    hipLaunchKernelGGL(w1prep, dim3(8), blk, 0, stream, rgb_w1, ir_w1, W1p);
    hipLaunchKernelGGL(conv1_mfma, dim3(4, 256, 8), blk, 0, stream, x, W1p, rgb_b1, C1h, C1l);
    hipLaunchKernelGGL(conv2_mfma, dim3(2, 128, 8), blk, 0, stream, C1h, C1l, rgb_w2, rgb_b2, Ahi, Alo, 0);
    hipLaunchKernelGGL(conv1_mfma, dim3(4, 256, 8), blk, 0, stream, x, W1p + 1024, ir_b1, C1h, C1l);
    hipLaunchKernelGGL(conv2_mfma, dim3(2, 128, 8), blk, 0, stream, C1h, C1l, ir_w2, ir_b2, Ahi, Alo, 64);
    hipLaunchKernelGGL(wprep, dim3(576), blk, 0, stream, fuse_w, Whi, Wlo, feat);
    hipLaunchKernelGGL(fuse_mfma, dim3(8, 64), blk, 0, stream, Ahi, Alo, Whi, Wlo, fuse_b, feat);
    hipLaunchKernelGGL(det_nms, dim3(1), dim3(64), 0, stream, feat, det_w, det_b, out);
}

// Round 9
// 478.000 us; speedup vs baseline: 1.4665x; 1.0457x over previous
//
#include <hip/hip_runtime.h>
#include <math.h>

// ---------------------------------------------------------------------------
// MultiStreamCNN. R22: conv2 single-pass rewrite. R18/R21's ky-phase conv2
// paid: B restaged 3x/block from stride-36B w2 reads (+f2bf reconvert,
// 37.7M redundant), 7 barriers/block, serial stage->compute. MFMA-ideal
// conv2 = 7 us; budget says it runs ~90-120 -> ~93% overhead. New form
// (fuse-style): stage ALL 9 B taps ONCE per block, coalesced float4 over
// flat w2 (18 iters/thread, LDS scatter); A fragments direct from C1
// global with 1-tap register prefetch (R17's proven loadA); 3 barriers
// total. LDS 73728B (B 9-tap hi+lo; pool unions on top) -> 2 blocks/CU.
// Per-acc FP term sequence identical (t=0..8; bh,bl,bh) -> bitwise-same.
// conv1/fuse/wprep/det byte-identical to R21.
// ---------------------------------------------------------------------------

typedef __bf16 bf16x8 __attribute__((ext_vector_type(8)));
typedef float f32x4 __attribute__((ext_vector_type(4)));

static __device__ __forceinline__ ushort f2bf(float f) {
    unsigned u = __float_as_uint(f);
    unsigned r = (u + 0x7fffu + ((u >> 16) & 1u)) >> 16;   // RNE
    return (ushort)r;
}
static __device__ __forceinline__ float bf2f(ushort h) {
    return __uint_as_float(((unsigned)h) << 16);
}

// ---------- w1prep: conv1 weights (both streams) -> packed hi|lo ------------
// W1p[s][oc][k] : k = c*9 + ky*3 + kx for k<27, zero-padded to 32.
__global__ __launch_bounds__(256) void w1prep(
    const float* __restrict__ w_rgb, const float* __restrict__ w_ir,
    uint* __restrict__ W1p)
{
    int i = blockIdx.x * 256 + threadIdx.x;
    if (i >= 2048) return;
    int s = i >> 10, r = i & 1023;
    int oc = r >> 5, k = r & 31;
    const float* w = s ? w_ir : w_rgb;
    float v = (k < 27) ? w[oc * 27 + k] : 0.f;   // [oc][c][ky][kx] linear == oc*27+k
    ushort h = f2bf(v);
    W1p[i] = (uint)h | ((uint)f2bf(v - bf2f(h)) << 16);
}

// ---------- Kernel A: conv3x3 (3->32) via MFMA + bias + relu + maxpool2 -----
__global__ __launch_bounds__(256) void conv1_mfma(
    const float* __restrict__ x, const uint* __restrict__ W1p,
    const float* __restrict__ bias, ushort* __restrict__ C1h,
    ushort* __restrict__ C1l)
{
    __shared__ uint S[3 * 4 * 132];          // packed hi|lo x tile, 6336 B
    __shared__ float pool[4][32][33];        // stride 33: no 16-way epilogue conflicts

    const int seg = blockIdx.x, Y = blockIdx.y, b = blockIdx.z;
    const int tid = threadIdx.x, wsub = tid >> 6, lane = tid & 63;
    const int n = lane & 15, q = lane >> 4;

    // B fragments from global packed W1p (4KB, L2-hot): oc = nt*16+n, k = q*8+e
    uint4 bu0a = *(const uint4*)&W1p[n * 32 + q * 8];
    uint4 bu0b = *(const uint4*)&W1p[n * 32 + q * 8 + 4];
    uint4 bu1a = *(const uint4*)&W1p[(16 + n) * 32 + q * 8];
    uint4 bu1b = *(const uint4*)&W1p[(16 + n) * 32 + q * 8 + 4];

    // stage x rows 2Y-1..2Y+2, cols seg*128-1..+128 (130 used, stride 132)
    const int ih0 = 2 * Y - 1, iw0 = seg * 128 - 1;
    for (int i = tid; i < 1584; i += 256) {
        int c = i / 528, rem = i - c * 528;
        int r = rem / 132, cc = rem - r * 132;
        int ih = ih0 + r, iw = iw0 + cc;
        float v = 0.f;
        if (cc < 130 && ih >= 0 && ih < 512 && iw >= 0 && iw < 512)
            v = x[((b * 3 + c) * 512 + ih) * 512 + iw];
        ushort h = f2bf(v);
        S[i] = (uint)h | ((uint)f2bf(v - bf2f(h)) << 16);
    }

    // unpack B into bf16x8 fragments (hi from low16, lo from high16)
    uint4 bh0v, bl0v, bh1v, bl1v;
    {
        uint u0[8], u1[8];
        *(uint4*)&u0[0] = bu0a; *(uint4*)&u0[4] = bu0b;
        *(uint4*)&u1[0] = bu1a; *(uint4*)&u1[4] = bu1b;
        uint* bh0 = (uint*)&bh0v; uint* bl0 = (uint*)&bl0v;
        uint* bh1 = (uint*)&bh1v; uint* bl1 = (uint*)&bl1v;
#pragma unroll
        for (int j = 0; j < 4; ++j) {
            bh0[j] = (u0[2 * j] & 0xffffu) | (u0[2 * j + 1] << 16);
            bl0[j] = (u0[2 * j] >> 16) | (u0[2 * j + 1] & 0xffff0000u);
            bh1[j] = (u1[2 * j] & 0xffffu) | (u1[2 * j + 1] << 16);
            bl1[j] = (u1[2 * j] >> 16) | (u1[2 * j + 1] & 0xffff0000u);
        }
    }
    bf16x8 Bh0 = __builtin_bit_cast(bf16x8, bh0v);
    bf16x8 Bl0 = __builtin_bit_cast(bf16x8, bl0v);
    bf16x8 Bh1 = __builtin_bit_cast(bf16x8, bh1v);
    bf16x8 Bl1 = __builtin_bit_cast(bf16x8, bl1v);

    // per-lane gather offsets: k = q*8+e -> (c,ky,kx)
    int idx[8];
    const int off0 = (wsub & 1) * 132 + (wsub >> 1) * 64 + n;
#pragma unroll
    for (int e = 0; e < 8; ++e) {
        int k = q * 8 + e;
        int c = (k >= 18) ? ((k >= 27) ? 3 : 2) : ((k >= 9) ? 1 : 0);
        int t = k - c * 9;
        int ky = (t >= 6) ? 2 : ((t >= 3) ? 1 : 0);
        int kx = t - ky * 3;
        idx[e] = (k < 27) ? ((c * 4 + ky) * 132 + kx + off0) : 0;  // k>=27: B=0
    }
    __syncthreads();

    f32x4 acc[4][2];
#pragma unroll
    for (int mt = 0; mt < 4; ++mt)
#pragma unroll
        for (int nt = 0; nt < 2; ++nt) acc[mt][nt] = (f32x4){0.f, 0.f, 0.f, 0.f};

#pragma unroll
    for (int mt = 0; mt < 4; ++mt) {
        uint u[8];
#pragma unroll
        for (int e = 0; e < 8; ++e) u[e] = S[idx[e] + mt * 16];
        uint4 ahv, alv;
        uint* ah = (uint*)&ahv;
        uint* al = (uint*)&alv;
#pragma unroll
        for (int j = 0; j < 4; ++j) {
            ah[j] = (u[2 * j] & 0xffffu) | (u[2 * j + 1] << 16);
            al[j] = (u[2 * j] >> 16) | (u[2 * j + 1] & 0xffff0000u);
        }
        bf16x8 Ah = __builtin_bit_cast(bf16x8, ahv);
        bf16x8 Al = __builtin_bit_cast(bf16x8, alv);
        __builtin_amdgcn_s_setprio(1);
        acc[mt][0] = __builtin_amdgcn_mfma_f32_16x16x32_bf16(Ah, Bh0, acc[mt][0], 0, 0, 0);
        acc[mt][1] = __builtin_amdgcn_mfma_f32_16x16x32_bf16(Ah, Bh1, acc[mt][1], 0, 0, 0);
        acc[mt][0] = __builtin_amdgcn_mfma_f32_16x16x32_bf16(Ah, Bl0, acc[mt][0], 0, 0, 0);
        acc[mt][1] = __builtin_amdgcn_mfma_f32_16x16x32_bf16(Ah, Bl1, acc[mt][1], 0, 0, 0);
        acc[mt][0] = __builtin_amdgcn_mfma_f32_16x16x32_bf16(Al, Bh0, acc[mt][0], 0, 0, 0);
        acc[mt][1] = __builtin_amdgcn_mfma_f32_16x16x32_bf16(Al, Bh1, acc[mt][1], 0, 0, 0);
        __builtin_amdgcn_s_setprio(0);
    }

    // pool x-pairs in-lane (D rows q*4+r are conv x), then row-pairs via LDS
#pragma unroll
    for (int mt = 0; mt < 4; ++mt)
#pragma unroll
        for (int nt = 0; nt < 2; ++nt) {
            int oc = nt * 16 + n;
            int plx = mt * 8 + q * 2;
            pool[wsub][plx][oc]     = fmaxf(acc[mt][nt][0], acc[mt][nt][1]);
            pool[wsub][plx + 1][oc] = fmaxf(acc[mt][nt][2], acc[mt][nt][3]);
        }
    __syncthreads();
    {
        int plx = tid >> 2, ocq = tid & 3;       // plx in [0,64), oc = ocq*8..+8
        int wp = plx >> 5, pl = plx & 31;
        __attribute__((aligned(16))) ushort hb[8], lb[8];
#pragma unroll
        for (int e = 0; e < 8; ++e) {
            int oc = ocq * 8 + e;
            float v = fmaxf(pool[wp * 2][pl][oc], pool[wp * 2 + 1][pl][oc]);
            v = fmaxf(v + bias[oc], 0.f);
            ushort h = f2bf(v);
            hb[e] = h;
            lb[e] = f2bf(v - bf2f(h));
        }
        int ow = seg * 64 + plx;
        size_t base = (((size_t)((b * 256 + Y) * 256 + ow)) << 5) + ocq * 8;
        *(uint4*)(C1h + base) = *(const uint4*)hb;
        *(uint4*)(C1l + base) = *(const uint4*)lb;
    }
}

// ---------- Kernel B: conv2 single-pass: B all-taps LDS + A global prefetch -
// Block: 2 conv rows (2Y, 2Y+1) x 128 px. Wave: rs=wsub&1 row, xs=wsub>>1
// x-half. B staged ONCE (9 taps, coalesced float4 over flat w2, LDS
// scatter); A fragments from C1 global per tap with 1-tap register
// prefetch. One staging barrier. FP order unchanged (t=0..8; bh,bl,bh).
__global__ __launch_bounds__(256) void conv2_mfma(
    const ushort* __restrict__ C1h, const ushort* __restrict__ C1l,
    const float* __restrict__ w2, const float* __restrict__ bias,
    ushort* __restrict__ Ahi, ushort* __restrict__ Alo, int stream_base)
{
    // B: [9][2048] hi (36864 B) + lo (36864 B). Pool unions on top (33280 B).
    __shared__ __attribute__((aligned(16))) char lds[73728];
    ushort* Bh = (ushort*)lds;
    ushort* Bl = (ushort*)(lds + 36864);
    float (*pool)[32][65] = (float (*)[32][65])lds;  // union, after all B reads

    const int seg = blockIdx.x, Y = blockIdx.y, b = blockIdx.z;
    const int tid = threadIdx.x, wsub = tid >> 6, lane = tid & 63;
    const int n = lane & 15, q = lane >> 4;
    const int yc = 2 * Y + (wsub & 1);              // conv row in [0,256)
    const int wx0 = seg * 128 + (wsub >> 1) * 64;   // conv x base for wave

    const uint4 zero4 = make_uint4(0u, 0u, 0u, 0u);

    auto loadA = [&](int t, uint4* aH, uint4* aL) {
        int ky = t / 3, kx = t - ky * 3;
        int yy = yc + ky - 1;
        bool yok = (yy >= 0) & (yy < 256);
#pragma unroll
        for (int mt = 0; mt < 4; ++mt) {
            int xp = wx0 + mt * 16 + n + kx - 1;
            bool ok = yok & (xp >= 0) & (xp < 256);
            int yyc = ok ? yy : 0, xpc = ok ? xp : 0;
            size_t off = (((size_t)((b * 256 + yyc) * 256 + xpc)) << 5) + q * 8;
            aH[mt] = ok ? *(const uint4*)(C1h + off) : zero4;
            aL[mt] = ok ? *(const uint4*)(C1l + off) : zero4;
        }
    };

    f32x4 acc[4][4];
#pragma unroll
    for (int mt = 0; mt < 4; ++mt)
#pragma unroll
        for (int nt = 0; nt < 4; ++nt) acc[mt][nt] = (f32x4){0.f, 0.f, 0.f, 0.f};

    uint4 aH[4], aL[4];
    loadA(0, aH, aL);

    // ---- stage ALL 9 B taps, coalesced: 18432 floats = 4608 float4 ---------
    for (int jj = tid; jj < 4608; jj += 256) {
        float4 w = *(const float4*)(w2 + jj * 4);
        float wv[4] = {w.x, w.y, w.z, w.w};
#pragma unroll
        for (int e = 0; e < 4; ++e) {
            int flat = jj * 4 + e;                 // (oc*32+kk)*9 + t
            int r = flat / 9, t = flat - r * 9;    // const-div -> magic mul
            ushort h = f2bf(wv[e]);
            Bh[t * 2048 + r] = h;
            Bl[t * 2048 + r] = f2bf(wv[e] - bf2f(h));
        }
    }
    __syncthreads();   // B staged; A tap-0 prefetch in flight per-lane

    for (int t = 0; t < 9; ++t) {
        uint4 cH[4], cL[4];
#pragma unroll
        for (int mt = 0; mt < 4; ++mt) { cH[mt] = aH[mt]; cL[mt] = aL[mt]; }
        if (t + 1 < 9) loadA(t + 1, aH, aL);
        bf16x8 bh[4], bl[4];
#pragma unroll
        for (int nt = 0; nt < 4; ++nt) {
            int off = t * 2048 + (nt * 16 + n) * 32 + q * 8;
            bh[nt] = __builtin_bit_cast(bf16x8, *(const uint4*)&Bh[off]);
            bl[nt] = __builtin_bit_cast(bf16x8, *(const uint4*)&Bl[off]);
        }
        // step-outer MFMA order (dep distance 16), identical FP order
        __builtin_amdgcn_s_setprio(1);
#pragma unroll
        for (int mt = 0; mt < 4; ++mt) {
            bf16x8 ah = __builtin_bit_cast(bf16x8, cH[mt]);
#pragma unroll
            for (int nt = 0; nt < 4; ++nt)
                acc[mt][nt] = __builtin_amdgcn_mfma_f32_16x16x32_bf16(ah, bh[nt], acc[mt][nt], 0, 0, 0);
        }
#pragma unroll
        for (int mt = 0; mt < 4; ++mt) {
            bf16x8 ah = __builtin_bit_cast(bf16x8, cH[mt]);
#pragma unroll
            for (int nt = 0; nt < 4; ++nt)
                acc[mt][nt] = __builtin_amdgcn_mfma_f32_16x16x32_bf16(ah, bl[nt], acc[mt][nt], 0, 0, 0);
        }
#pragma unroll
        for (int mt = 0; mt < 4; ++mt) {
            bf16x8 al = __builtin_bit_cast(bf16x8, cL[mt]);
#pragma unroll
            for (int nt = 0; nt < 4; ++nt)
                acc[mt][nt] = __builtin_amdgcn_mfma_f32_16x16x32_bf16(al, bh[nt], acc[mt][nt], 0, 0, 0);
        }
        __builtin_amdgcn_s_setprio(0);
    }

    __syncthreads();   // all B reads done; safe to overwrite with pool

#pragma unroll
    for (int mt = 0; mt < 4; ++mt)
#pragma unroll
        for (int nt = 0; nt < 4; ++nt) {
            int oc = nt * 16 + n;
            int plx = mt * 8 + q * 2;
            pool[wsub][plx][oc]     = fmaxf(acc[mt][nt][0], acc[mt][nt][1]);
            pool[wsub][plx + 1][oc] = fmaxf(acc[mt][nt][2], acc[mt][nt][3]);
        }
    __syncthreads();

    {
        int plx = tid >> 2, ocq = tid & 3;
        int wp = plx >> 5, pl = plx & 31;
        __attribute__((aligned(16))) ushort hb[16], lb[16];
#pragma unroll
        for (int e = 0; e < 16; ++e) {
            int oc = ocq * 16 + e;
            float v = fmaxf(pool[wp * 2][pl][oc], pool[wp * 2 + 1][pl][oc]);
            v = fmaxf(v + bias[oc], 0.f);
            ushort h = f2bf(v);
            hb[e] = h;
            lb[e] = f2bf(v - bf2f(h));
        }
        int gx = seg * 64 + plx;
        int cpl = (stream_base >> 5) + (ocq >> 1);
        int cho = (ocq & 1) * 16;
        size_t base = (((size_t)(((b * 4 + cpl) * 128 + Y) * 128 + gx)) << 5) + cho;
        uint4* dh = (uint4*)(Ahi + base);
        uint4* dl = (uint4*)(Alo + base);
        dh[0] = *(const uint4*)&hb[0];
        dh[1] = *(const uint4*)&hb[8];
        dl[0] = *(const uint4*)&lb[0];
        dl[1] = *(const uint4*)&lb[8];
    }
}

// ---------- wprep: fuse_w fp32 -> fragment-ordered bf16 hi/lo + feat zero ---
// CHUNK-MAJOR: Wf[c][t][oc][kk] = W[oc][ic=c*32+kk][ky=t/3][kx=t%3].
__global__ __launch_bounds__(256) void wprep(
    const float* __restrict__ fw, ushort* __restrict__ Whi,
    ushort* __restrict__ Wlo, float* __restrict__ feat)
{
    int idx = blockIdx.x * 256 + threadIdx.x;
    if (idx < 1024) feat[idx] = 0.f;
    if (idx >= 147456) return;
    int kk = idx & 31;
    int oc = (idx >> 5) & 127;
    int ct = idx >> 12;           // 0..35 = c*9 + t
    int c = ct / 9, t = ct - c * 9;
    int ic = c * 32 + kk;
    int ky = t / 3, kx = t - ky * 3;
    float v = fw[((oc * 128 + ic) * 3 + ky) * 3 + kx];
    ushort h = f2bf(v);
    Whi[idx] = h;
    Wlo[idx] = f2bf(v - bf2f(h));
}

// ---------- Kernel C: fuse conv via split-bf16 MFMA + relu + global mean ----
// R13/R14/R17/R18 shape (256px x 128oc, wave = 64px x 128oc) + rolling
// 4-deep register prefetch of B. NO setprio (reg-ceiling, R16 spill lesson).
__global__ __launch_bounds__(256, 2) void fuse_mfma(
    const ushort* __restrict__ Ahi, const ushort* __restrict__ Alo,
    const ushort* __restrict__ Whi, const ushort* __restrict__ Wlo,
    const float* __restrict__ bias, float* __restrict__ featsum)
{
    __shared__ float partial[4][128];
    const int b = blockIdx.x, ypair = blockIdx.y;
    const int tid = threadIdx.x, wsub = tid >> 6, lane = tid & 63;
    const int n = lane & 15, q = lane >> 4;
    const int y = ypair * 2 + (wsub >> 1);       // conv row for this wave
    const int xbase = (wsub & 1) * 64;           // wave covers x [xbase,xbase+64)

    f32x4 acc[4][8];
#pragma unroll
    for (int mt = 0; mt < 4; ++mt)
#pragma unroll
        for (int g = 0; g < 8; ++g) acc[mt][g] = (f32x4){0.f, 0.f, 0.f, 0.f};

    const uint4 zero4 = make_uint4(0u, 0u, 0u, 0u);

    auto loadA = [&](int tc, uint4* oh, uint4* ol) {
        int c = tc / 9, t = tc - c * 9;   // chunk-major decode
        int ky = t / 3, kx = t - ky * 3;
        int yy = y + ky - 1;
        bool yok = (yy >= 0) & (yy < 128);
#pragma unroll
        for (int mt = 0; mt < 4; ++mt) {
            int xp = xbase + mt * 16 + n + kx - 1;
            bool ok = yok & (xp >= 0) & (xp < 128);
            int yyc = ok ? yy : 0, xpc = ok ? xp : 0;
            size_t aoff = (((size_t)(((b * 4 + c) * 128 + yyc) * 128 + xpc)) << 5) + q * 8;
            oh[mt] = ok ? *(const uint4*)(Ahi + aoff) : zero4;
            ol[mt] = ok ? *(const uint4*)(Alo + aoff) : zero4;
        }
    };

    uint4 pAh[4], pAl[4];
    loadA(0, pAh, pAl);

    // lane-fixed B base; step address = base + s*512, s = tc*8+g
    const ushort* WhiB = Whi + n * 32 + q * 8;
    const ushort* WloB = Wlo + n * 32 + q * 8;

    // rolling 4-deep B prefetch buffer
    uint4 nBh[4], nBl[4];
#pragma unroll
    for (int j = 0; j < 4; ++j) {
        nBh[j] = *(const uint4*)(WhiB + j * 512);
        nBl[j] = *(const uint4*)(WloB + j * 512);
    }

    for (int tc = 0; tc < 36; ++tc) {
        uint4 cAh[4], cAl[4];
#pragma unroll
        for (int mt = 0; mt < 4; ++mt) { cAh[mt] = pAh[mt]; cAl[mt] = pAl[mt]; }
        if (tc + 1 < 36) loadA(tc + 1, pAh, pAl);
#pragma unroll
        for (int g = 0; g < 8; ++g) {
            const int slot = g & 3;
            bf16x8 bh = __builtin_bit_cast(bf16x8, nBh[slot]);
            bf16x8 bl = __builtin_bit_cast(bf16x8, nBl[slot]);
            // prefetch step s+4 (tail reads 4 padded never-consumed steps)
            {
                size_t off = (size_t)(tc * 8 + g + 4) * 512;
                nBh[slot] = *(const uint4*)(WhiB + off);
                nBl[slot] = *(const uint4*)(WloB + off);
            }
#pragma unroll
            for (int mt = 0; mt < 4; ++mt) {
                bf16x8 ah = __builtin_bit_cast(bf16x8, cAh[mt]);
                acc[mt][g] = __builtin_amdgcn_mfma_f32_16x16x32_bf16(ah, bh, acc[mt][g], 0, 0, 0);
            }
#pragma unroll
            for (int mt = 0; mt < 4; ++mt) {
                bf16x8 ah = __builtin_bit_cast(bf16x8, cAh[mt]);
                acc[mt][g] = __builtin_amdgcn_mfma_f32_16x16x32_bf16(ah, bl, acc[mt][g], 0, 0, 0);
            }
#pragma unroll
            for (int mt = 0; mt < 4; ++mt) {
                bf16x8 al = __builtin_bit_cast(bf16x8, cAl[mt]);
                acc[mt][g] = __builtin_amdgcn_mfma_f32_16x16x32_bf16(al, bh, acc[mt][g], 0, 0, 0);
            }
        }
    }

    // Epilogue: lane (q,n) of tile (mt,g) holds D[px = q*4+r][oc = g*16+n].
#pragma unroll
    for (int g = 0; g < 8; ++g) {
        float bv = bias[g * 16 + n];
        float v = 0.f;
#pragma unroll
        for (int mt = 0; mt < 4; ++mt)
#pragma unroll
            for (int r = 0; r < 4; ++r) v += fmaxf(acc[mt][g][r] + bv, 0.f);
        v += __shfl_xor(v, 16);
        v += __shfl_xor(v, 32);
        if (lane < 16) partial[wsub][g * 16 + lane] = v;
    }
    __syncthreads();
    if (tid < 128) {
        float v = partial[0][tid] + partial[1][tid] + partial[2][tid] + partial[3][tid];
        atomicAdd(&featsum[b * 128 + tid], v);
    }
}

// ---------- Kernel D: det head + sigmoid + NMS + outputs --------------------
__global__ void det_nms(const float* __restrict__ featsum,
                        const float* __restrict__ dw, const float* __restrict__ db,
                        float* __restrict__ out)
{
    const int b = threadIdx.x;
    if (b >= 8) return;
    const float inv = 1.0f / 16384.0f;

    float p[18];
    for (int j = 0; j < 18; ++j) {
        float a = db[j];
        const float* wp = &dw[j * 128];
        const float* f = &featsum[b * 128];
        for (int c = 0; c < 128; ++c) a = fmaf(wp[c], f[c] * inv, a);
        p[j] = a;
    }
    for (int a = 0; a < 3; ++a)
        for (int e = 0; e < 6; ++e) out[b * 18 + a * 6 + e] = p[a * 6 + e];

    float bx[3][4], sc[3];
    bool ck[3];
    for (int a = 0; a < 3; ++a) {
        for (int k = 0; k < 4; ++k) {
            bx[a][k] = p[a * 6 + k];
            out[144 + b * 12 + a * 4 + k] = bx[a][k];
        }
        float sg = 1.f / (1.f + expf(-p[a * 6 + 4]));
        sc[a] = sg;
        ck[a] = sg > 0.5f;
        out[240 + b * 3 + a] = sg;
    }

    float key[3];
    int order[3];
    bool used[3] = {false, false, false};
    for (int a = 0; a < 3; ++a) key[a] = ck[a] ? sc[a] : -INFINITY;
    for (int i = 0; i < 3; ++i) {
        int best = -1;
        float bk = 0.f;
        for (int a = 0; a < 3; ++a) {
            if (used[a]) continue;
            if (best < 0 || key[a] > bk) { best = a; bk = key[a]; }
        }
        order[i] = best;
        used[best] = true;
    }

    float X1[3], Y1[3], X2[3], Y2[3], AR[3];
    for (int i = 0; i < 3; ++i) {
        int o = order[i];
        X1[i] = bx[o][0]; Y1[i] = bx[o][1];
        X2[i] = bx[o][2]; Y2[i] = bx[o][3];
        AR[i] = (X2[i] - X1[i]) * (Y2[i] - Y1[i]);
    }
    bool suppressed[3] = {false, false, false}, keep_s[3];
    for (int i = 0; i < 3; ++i) {
        bool valid = !suppressed[i];
        keep_s[i] = valid;
        if (valid) {
            for (int j = i + 1; j < 3; ++j) {
                float ix1 = fmaxf(X1[i], X1[j]), iy1 = fmaxf(Y1[i], Y1[j]);
                float ix2 = fminf(X2[i], X2[j]), iy2 = fminf(Y2[i], Y2[j]);
                float inter = fmaxf(ix2 - ix1, 0.f) * fmaxf(iy2 - iy1, 0.f);
                float iou = inter / (AR[i] + AR[j] - inter);
                if (iou > 0.5f) suppressed[j] = true;
            }
        }
    }
    bool keep[3];
    for (int i = 0; i < 3; ++i) keep[order[i]] = keep_s[i];
    for (int a = 0; a < 3; ++a)
        out[264 + b * 3 + a] = (keep[a] && ck[a]) ? 1.f : 0.f;
}

// ---------------------------------------------------------------------------
extern "C" void kernel_launch(void* const* d_in, const int* in_sizes, int n_in,
                              void* d_out, int out_size, void* d_ws, size_t ws_size,
                              hipStream_t stream)
{
    const float* x      = (const float*)d_in[0];
    const float* rgb_w1 = (const float*)d_in[1];
    const float* rgb_b1 = (const float*)d_in[2];
    const float* rgb_w2 = (const float*)d_in[3];
    const float* rgb_b2 = (const float*)d_in[4];
    const float* ir_w1  = (const float*)d_in[5];
    const float* ir_b1  = (const float*)d_in[6];
    const float* ir_w2  = (const float*)d_in[7];
    const float* ir_b2  = (const float*)d_in[8];
    const float* fuse_w = (const float*)d_in[9];
    const float* fuse_b = (const float*)d_in[10];
    const float* det_w  = (const float*)d_in[11];
    const float* det_b  = (const float*)d_in[12];
    float* out = (float*)d_out;

    char* ws = (char*)d_ws;
    ushort* C1h  = (ushort*)(ws);                         // 33,554,432 B
    ushort* C1l  = (ushort*)(ws + 33554432);              // 33,554,432 B
    // post-conv2 reuse of the C1 region:
    ushort* Whi  = (ushort*)(ws);                         // 294,912 B
    ushort* Wlo  = (ushort*)(ws + 299008);                // 294,912 B
    float*  feat = (float*)(ws + 598016);                 // 4,096 B
    ushort* Ahi  = (ushort*)(ws + 67108864);              // 33,554,432 B
    ushort* Alo  = (ushort*)(ws + 100663296);             // 33,554,432 B
    // W1p (8 KB) parked in the TAIL of Alo: bytes [134209536, 134217728).
    // Written ONLY by conv2_mfma(ir) (plane b=7,cpl=3), after both
    // conv1_mfma dispatches have consumed W1p.
    uint*   W1p  = (uint*)(ws + 134209536);

    dim3 blk(256);
    hipLaunchKernelGGL(w1prep, dim3(8), blk, 0, stream, rgb_w1, ir_w1, W1p);
    hipLaunchKernelGGL(conv1_mfma, dim3(4, 256, 8), blk, 0, stream, x, W1p, rgb_b1, C1h, C1l);
    hipLaunchKernelGGL(conv2_mfma, dim3(2, 128, 8), blk, 0, stream, C1h, C1l, rgb_w2, rgb_b2, Ahi, Alo, 0);
    hipLaunchKernelGGL(conv1_mfma, dim3(4, 256, 8), blk, 0, stream, x, W1p + 1024, ir_b1, C1h, C1l);
    hipLaunchKernelGGL(conv2_mfma, dim3(2, 128, 8), blk, 0, stream, C1h, C1l, ir_w2, ir_b2, Ahi, Alo, 64);
    hipLaunchKernelGGL(wprep, dim3(576), blk, 0, stream, fuse_w, Whi, Wlo, feat);
    hipLaunchKernelGGL(fuse_mfma, dim3(8, 64), blk, 0, stream, Ahi, Alo, Whi, Wlo, fuse_b, feat);
    hipLaunchKernelGGL(det_nms, dim3(1), dim3(64), 0, stream, feat, det_w, det_b, out);
}